// Round 5
// baseline (167.309 us; speedup 1.0000x reference)
//
#include <hip/hip_runtime.h>
#include <hip/hip_bf16.h>
#include <math.h>

#define BS 16
#define Q 1024
#define CC 92
#define T 128
#define M 1024   // columns in transposed problem (= Q)
#define NR 128   // rows in transposed problem (= T)
#define NQB 16   // q-blocks of 64 per batch

// ---------------------------------------------------------------------------
// Fused prep kernel: one block per (b, 64-q slab).
//  - stages logits slab in LDS
//  - per-q softmax stats with IDENTICAL reduction sequence to R1-R4 cost
//    kernel (Cb stays bit-identical)
//  - computes 64q x 128t cost tile once
//  - writes Cb[b][q][t] (coalesced float4)
//  - writes CbT[b][t][q] via LDS transpose (coalesced float4)
//  - emits per-(t, qblock) partial rowmin keys: (mono32(cost)<<10)|j
// Replaces cost + transpose + rowmin kernels (4 launches -> 2).
// ---------------------------------------------------------------------------
__global__ __launch_bounds__(256) void prep_kernel(
    const float* __restrict__ logits,   // [BS][Q][CC]
    const float* __restrict__ ppts,     // [BS][Q][2]
    const int*   __restrict__ tlab,     // [BS][T]
    const float* __restrict__ tpts,     // [BS][T][2]
    float* __restrict__ Cb,             // [BS][Q][T]
    float* __restrict__ CbT,            // [BS][NR][Q]
    unsigned long long* __restrict__ part)  // [BS][NR][NQB]
{
    const int blk = blockIdx.x;         // 0..BS*NQB-1
    const int b   = blk >> 4;
    const int qb  = blk & 15;
    const int q0  = qb * 64;
    const int tid = threadIdx.x;
    const int lane = tid & 63;

    __shared__ float lg[64 * CC];       // logits slab, [ql][c]
    __shared__ float tile[128][68];     // [t][ql], pitch 68 for b128 align
    __shared__ float tx_sh[T], ty_sh[T];
    __shared__ int   lab_sh[T];
    __shared__ float mx_sh[64], inv_sh[64], px_sh[64], py_sh[64];

    if (tid < T) {
        lab_sh[tid] = tlab[b * T + tid];
        tx_sh[tid]  = tpts[(b * T + tid) * 2 + 0];
        ty_sh[tid]  = tpts[(b * T + tid) * 2 + 1];
    }
    if (tid < 64) {
        px_sh[tid] = ppts[((size_t)b * Q + q0 + tid) * 2 + 0];
        py_sh[tid] = ppts[((size_t)b * Q + q0 + tid) * 2 + 1];
    }
    const float* lbase = logits + ((size_t)b * Q + q0) * CC;
    for (int idx = tid; idx < 64 * CC; idx += 256) lg[idx] = lbase[idx];
    __syncthreads();

    // softmax stats: wave w handles q_l = w*16 .. w*16+15, lanes over classes.
    // EXACT same op sequence as the R1-R4 cost kernel -> bit-identical Cb.
    {
        const int w = tid >> 6;
        for (int s = 0; s < 16; ++s) {
            const int ql = w * 16 + s;
            const float* c = &lg[ql * CC];
            float l0 = c[lane];
            float l1 = (lane + 64 < CC) ? c[lane + 64] : -INFINITY;
            float mx = fmaxf(l0, l1);
            #pragma unroll
            for (int off = 32; off > 0; off >>= 1)
                mx = fmaxf(mx, __shfl_down(mx, off));
            mx = __shfl(mx, 0);
            float es = expf(l0 - mx) + ((lane + 64 < CC) ? expf(l1 - mx) : 0.0f);
            #pragma unroll
            for (int off = 32; off > 0; off >>= 1) es += __shfl_down(es, off);
            es = __shfl(es, 0);
            if (lane == 0) { mx_sh[ql] = mx; inv_sh[ql] = 1.0f / es; }
        }
    }
    __syncthreads();

    // tile compute + Cb write: thread = (ql = tid>>2, tc = tid&3)
    {
        const int ql = tid >> 2;
        const int tc = tid & 3;
        const float px = px_sh[ql], py = py_sh[ql];
        const float mx = mx_sh[ql], inv = inv_sh[ql];
        const float* lgq = &lg[ql * CC];
        float* cbrow = Cb + ((size_t)b * Q + q0 + ql) * T + tc * 32;
        #pragma unroll
        for (int k = 0; k < 8; ++k) {
            float4 o;
            #pragma unroll
            for (int e = 0; e < 4; ++e) {
                const int t = tc * 32 + 4 * k + e;
                const int labv = lab_sh[t];
                float prob = expf(lgq[labv] - mx) * inv;
                float cp   = fabsf(px - tx_sh[t]) + fabsf(py - ty_sh[t]);
                float val  = cp - prob;
                (&o.x)[e] = val;
                tile[t][ql] = val;
            }
            ((float4*)cbrow)[k] = o;
        }
    }
    __syncthreads();

    // CbT write + rowmin partials: thread = (rg = tid>>4, c4 = tid&15)
    {
        const int rg = tid >> 4;
        const int c4 = tid & 15;
        #pragma unroll
        for (int it = 0; it < 8; ++it) {
            const int t = it * 16 + rg;
            float4 v = *(const float4*)&tile[t][4 * c4];
            *(float4*)(CbT + ((size_t)b * NR + t) * Q + q0 + 4 * c4) = v;

            unsigned long long bk = ~0ull;
            const float* vf = (const float*)&v;
            #pragma unroll
            for (int e = 0; e < 4; ++e) {
                unsigned bits = __float_as_uint(vf[e]);
                unsigned mono = (bits & 0x80000000u) ? ~bits
                                                     : (bits | 0x80000000u);
                const int j = q0 + 4 * c4 + e;
                unsigned long long key =
                    ((unsigned long long)mono << 10) | (unsigned)j;
                bk = (key < bk) ? key : bk;
            }
            #pragma unroll
            for (int off = 1; off < 16; off <<= 1) {
                unsigned long long ok = __shfl_xor(bk, off);
                bk = (ok < bk) ? ok : bk;
            }
            if (c4 == 0) part[((size_t)b * NR + t) * NQB + qb] = bk;
        }
    }
}

// ---------------------------------------------------------------------------
// Fallback cost kernel (only used if workspace is too small). Same as R1-R4.
// ---------------------------------------------------------------------------
__global__ __launch_bounds__(256) void cost_kernel(
    const float* __restrict__ logits, const float* __restrict__ ppts,
    const int* __restrict__ tlab, const float* __restrict__ tpts,
    float* __restrict__ Cb)
{
    const int blk  = blockIdx.x;
    const int b    = blk >> 8;
    const int wave = threadIdx.x >> 6;
    const int lane = threadIdx.x & 63;
    const int q    = (blk & 255) * 4 + wave;

    __shared__ float tx_sh[T], ty_sh[T];
    __shared__ int   lab_sh[T];
    __shared__ float logit_sh[4][CC];

    if (threadIdx.x < T) {
        lab_sh[threadIdx.x] = tlab[b * T + threadIdx.x];
        tx_sh[threadIdx.x]  = tpts[(b * T + threadIdx.x) * 2 + 0];
        ty_sh[threadIdx.x]  = tpts[(b * T + threadIdx.x) * 2 + 1];
    }
    const float* lrow = logits + ((size_t)b * Q + q) * CC;
    float l0 = lrow[lane];
    float l1 = (lane + 64 < CC) ? lrow[lane + 64] : -INFINITY;
    logit_sh[wave][lane] = l0;
    if (lane + 64 < CC) logit_sh[wave][lane + 64] = l1;

    float mx = fmaxf(l0, l1);
    #pragma unroll
    for (int off = 32; off > 0; off >>= 1) mx = fmaxf(mx, __shfl_down(mx, off));
    mx = __shfl(mx, 0);
    float es = expf(l0 - mx) + ((lane + 64 < CC) ? expf(l1 - mx) : 0.0f);
    #pragma unroll
    for (int off = 32; off > 0; off >>= 1) es += __shfl_down(es, off);
    es = __shfl(es, 0);
    const float inv = 1.0f / es;
    const float px = ppts[((size_t)b * Q + q) * 2 + 0];
    const float py = ppts[((size_t)b * Q + q) * 2 + 1];
    __syncthreads();
    float* outrow = Cb + ((size_t)b * Q + q) * T;
    #pragma unroll
    for (int t = lane; t < T; t += 64) {
        int   labv = lab_sh[t];
        float prob = expf(logit_sh[wave][labv] - mx) * inv;
        float cp   = fabsf(px - tx_sh[t]) + fabsf(py - ty_sh[t]);
        outrow[t]  = cp - prob;
    }
}

// ---------------------------------------------------------------------------
// Kernel 2: JV solver. ONE WAVE per batch. (search loop unchanged from R4)
// Lane L owns columns j = 256*g + 4*L + e  (g=0..3, e=0..3, k = 4g+e).
// Greedy init from prep's partial rowmin keys, then fp64 shortest augmenting
// path (scipy variant) for leftover rows.
// ---------------------------------------------------------------------------
template<int USET>
__global__ __launch_bounds__(64) void solve_kernel(
    const float* __restrict__ Cb,    // [BS][Q][T] fallback (strided)
    const float* __restrict__ CbT,   // [BS][NR][Q] row-major solver cost
    const unsigned long long* __restrict__ part,  // [BS][NR][NQB] or nullptr
    float* __restrict__ out_rows,    // [BS][T]
    float* __restrict__ out_cols)    // [BS][T]
{
    const int b    = blockIdx.x;
    const int lane = threadIdx.x;    // 0..63

    __shared__ int    row4col[M];    // col j -> row (-1 free)
    __shared__ int    col4row[NR];   // row i -> col (-1 free)
    __shared__ double u_sh[NR];
    __shared__ int    path_lds[M];   // swizzled: A(j) = 256g + 64e + L
    __shared__ int    SRr[NR];       // rows that joined SR (excl. curRow)
    __shared__ double SRd[NR];       // dist at which they joined
    __shared__ int    minj_sh[NR];   // greedy: per-row argmin column

    const float* CbB  = Cb  + (size_t)b * Q * T;
    const float* CbTB = CbT + (size_t)b * NR * Q;

    for (int j = lane; j < M;  j += 64) row4col[j] = -1;
    for (int i = lane; i < NR; i += 64) col4row[i] = -1;

    // reduce prep's partial keys -> u duals + greedy argmin columns
    if (part) {
        for (int r = lane; r < NR; r += 64) {
            const unsigned long long* pr = part + ((size_t)b * NR + r) * NQB;
            unsigned long long k = pr[0];
            #pragma unroll
            for (int i = 1; i < NQB; ++i) {
                unsigned long long o = pr[i];
                k = (o < k) ? o : k;
            }
            minj_sh[r] = (int)(k & 1023u);
            unsigned mono = (unsigned)(k >> 10);
            unsigned bits = (mono & 0x80000000u) ? (mono ^ 0x80000000u) : ~mono;
            u_sh[r] = (double)__uint_as_float(bits);
        }
    } else {
        for (int i = lane; i < NR; i += 64) { minj_sh[i] = -1; u_sh[i] = 0.0; }
    }
    __syncthreads();

    // greedy first-come-first-served: row i wins col j iff it is the first
    // row whose argmin is j (parallel first-occurrence, broadcast LDS reads)
    if (part) {
        for (int i = lane; i < NR; i += 64) {
            const int mj = minj_sh[i];
            int first = -1;
            for (int t2 = 0; t2 < NR; ++t2)
                if (first < 0 && minj_sh[t2] == mj) first = t2;
            if (first == i) { col4row[i] = mj; row4col[mj] = i; }
        }
        __syncthreads();
    }

    const double DINF = (double)INFINITY;
    double v_[16], dist_[16];
    #pragma unroll
    for (int k = 0; k < 16; ++k) v_[k] = 0.0;

    for (int curRow = 0; curRow < NR; ++curRow) {
        if (col4row[curRow] >= 0) continue;            // greedy got it

        #pragma unroll
        for (int k = 0; k < 16; ++k) dist_[k] = DINF;
        unsigned used  = 0;          // SC bitmask, bit k
        double   minVal = 0.0;
        int      i_s  = curRow;
        int      sink = -1;
        int      cnt  = 0;

        for (int guard = 0; guard <= M; ++guard) {
            const double ui = u_sh[i_s];
            const double s  = minVal - ui;

            float4 c4[4];
            if (USET) {
                const float4* row = (const float4*)(CbTB + (size_t)i_s * Q);
                #pragma unroll
                for (int g = 0; g < 4; ++g) c4[g] = row[lane + 64 * g];
            } else {
                const float* col = CbB + i_s;
                #pragma unroll
                for (int g = 0; g < 4; ++g) {
                    float* cf = (float*)&c4[g];
                    #pragma unroll
                    for (int e = 0; e < 4; ++e)
                        cf[e] = col[(size_t)(256 * g + 4 * lane + e) * T];
                }
            }

            double lmin = DINF; int lidx = 0x7fffffff;
            #pragma unroll
            for (int g = 0; g < 4; ++g) {
                const float* cf = (const float*)&c4[g];
                #pragma unroll
                for (int e = 0; e < 4; ++e) {
                    const int k = 4 * g + e;
                    const int j = 256 * g + 4 * lane + e;   // ascending in k
                    const bool fr = ((used >> k) & 1u) == 0u;
                    double r = s + (double)cf[e] - v_[k];
                    if (fr && r < dist_[k]) {
                        dist_[k] = r;
                        path_lds[256 * g + 64 * e + lane] = i_s;  // swizzled
                    }
                    double a = fr ? dist_[k] : DINF;
                    if (a < lmin) { lmin = a; lidx = j; }
                }
            }

            // speculative owner lookup for this lane's candidate (hides the
            // dependent row4col LDS latency behind the butterfly)
            const int cand = row4col[(lidx < M) ? lidx : 0];

            // wave argmin butterfly (value, then smaller index)
            double bv = lmin; int bj = lidx;
            #pragma unroll
            for (int off = 32; off > 0; off >>= 1) {
                double ov = __shfl_xor(bv, off);
                int    oj = __shfl_xor(bj, off);
                if (ov < bv || (ov == bv && oj < bj)) { bv = ov; bj = oj; }
            }
            minVal = bv;
            const int jstar = __builtin_amdgcn_readfirstlane(bj);

            if (((jstar >> 2) & 63) == lane)
                used |= (1u << (((jstar >> 8) << 2) | (jstar & 3)));

            const int ra =
                __builtin_amdgcn_readfirstlane(__shfl(cand, (jstar >> 2) & 63));
            if (ra == -1) { sink = jstar; break; }
            if (lane == 0 && cnt < NR) { SRr[cnt] = ra; SRd[cnt] = bv; }
            cnt++;
            i_s = ra;
        }

        // dual updates (scipy style, out of loop)
        #pragma unroll
        for (int k = 0; k < 16; ++k)
            if ((used >> k) & 1u) v_[k] += dist_[k] - minVal;

        if (lane == 0) u_sh[curRow] += minVal;
        for (int t = lane; t < cnt; t += 64)
            u_sh[SRr[t]] += minVal - SRd[t];

        // augment along path (serial, lane 0)
        if (lane == 0) {
            int j = sink;
            for (int g2 = 0; g2 < NR + 2; ++g2) {
                int pi = path_lds[((j >> 8) << 8) | ((j & 3) << 6) |
                                  ((j >> 2) & 63)];
                row4col[j] = pi;
                int jn = col4row[pi];
                col4row[pi] = j;
                if (pi == curRow) break;
                j = jn;
            }
        }
        __syncthreads();
    }

    // outputs: row_idx = sorted q, col_idx = matching t
    for (int t = lane; t < NR; t += 64) {
        int q = col4row[t];
        int rank = 0;
        for (int t2 = 0; t2 < NR; ++t2) rank += (col4row[t2] < q);
        out_rows[b * NR + rank] = (float)q;
        out_cols[b * NR + rank] = (float)t;
    }
}

// ---------------------------------------------------------------------------
extern "C" void kernel_launch(void* const* d_in, const int* in_sizes, int n_in,
                              void* d_out, int out_size, void* d_ws, size_t ws_size,
                              hipStream_t stream) {
    const float* logits = (const float*)d_in[0];
    const float* ppts   = (const float*)d_in[1];
    const int*   tlab   = (const int*)  d_in[2];
    const float* tpts   = (const float*)d_in[3];

    float* Cb   = (float*)d_out;                 // BS*Q*T floats
    float* rows = Cb + (size_t)BS * Q * T;       // BS*T floats
    float* cols = rows + (size_t)BS * T;         // BS*T floats

    float* CbT = (float*)d_ws;                               // 8 MiB
    unsigned long long* part =
        (unsigned long long*)((char*)d_ws + (size_t)BS * NR * Q * sizeof(float));

    const size_t need = (size_t)BS * NR * Q * sizeof(float)
                      + (size_t)BS * NR * NQB * sizeof(unsigned long long);

    if (ws_size >= need) {
        prep_kernel<<<BS * NQB, 256, 0, stream>>>(logits, ppts, tlab, tpts,
                                                  Cb, CbT, part);
        solve_kernel<1><<<BS, 64, 0, stream>>>(Cb, CbT, part, rows, cols);
    } else {
        cost_kernel<<<4096, 256, 0, stream>>>(logits, ppts, tlab, tpts, Cb);
        solve_kernel<0><<<BS, 64, 0, stream>>>(Cb, CbT, nullptr, rows, cols);
    }
}

// Round 6
// 148.647 us; speedup vs baseline: 1.1255x; 1.1255x over previous
//
#include <hip/hip_runtime.h>
#include <hip/hip_bf16.h>
#include <math.h>

#define BS 16
#define Q 1024
#define CC 92
#define T 128
#define M 1024   // columns in transposed problem (= Q)
#define NR 128   // rows in transposed problem (= T)
#define NQB 16   // q-blocks of 64 per batch

// ---------------------------------------------------------------------------
// Fused prep kernel (unchanged from R5 — bit-identical Cb, passed absmax 0).
// ---------------------------------------------------------------------------
__global__ __launch_bounds__(256) void prep_kernel(
    const float* __restrict__ logits,   // [BS][Q][CC]
    const float* __restrict__ ppts,     // [BS][Q][2]
    const int*   __restrict__ tlab,     // [BS][T]
    const float* __restrict__ tpts,     // [BS][T][2]
    float* __restrict__ Cb,             // [BS][Q][T]
    float* __restrict__ CbT,            // [BS][NR][Q]
    unsigned long long* __restrict__ part)  // [BS][NR][NQB]
{
    const int blk = blockIdx.x;         // 0..BS*NQB-1
    const int b   = blk >> 4;
    const int qb  = blk & 15;
    const int q0  = qb * 64;
    const int tid = threadIdx.x;
    const int lane = tid & 63;

    __shared__ float lg[64 * CC];       // logits slab, [ql][c]
    __shared__ float tile[128][68];     // [t][ql], pitch 68 for b128 align
    __shared__ float tx_sh[T], ty_sh[T];
    __shared__ int   lab_sh[T];
    __shared__ float mx_sh[64], inv_sh[64], px_sh[64], py_sh[64];

    if (tid < T) {
        lab_sh[tid] = tlab[b * T + tid];
        tx_sh[tid]  = tpts[(b * T + tid) * 2 + 0];
        ty_sh[tid]  = tpts[(b * T + tid) * 2 + 1];
    }
    if (tid < 64) {
        px_sh[tid] = ppts[((size_t)b * Q + q0 + tid) * 2 + 0];
        py_sh[tid] = ppts[((size_t)b * Q + q0 + tid) * 2 + 1];
    }
    const float* lbase = logits + ((size_t)b * Q + q0) * CC;
    for (int idx = tid; idx < 64 * CC; idx += 256) lg[idx] = lbase[idx];
    __syncthreads();

    // softmax stats: EXACT same op sequence as original cost kernel.
    {
        const int w = tid >> 6;
        for (int s = 0; s < 16; ++s) {
            const int ql = w * 16 + s;
            const float* c = &lg[ql * CC];
            float l0 = c[lane];
            float l1 = (lane + 64 < CC) ? c[lane + 64] : -INFINITY;
            float mx = fmaxf(l0, l1);
            #pragma unroll
            for (int off = 32; off > 0; off >>= 1)
                mx = fmaxf(mx, __shfl_down(mx, off));
            mx = __shfl(mx, 0);
            float es = expf(l0 - mx) + ((lane + 64 < CC) ? expf(l1 - mx) : 0.0f);
            #pragma unroll
            for (int off = 32; off > 0; off >>= 1) es += __shfl_down(es, off);
            es = __shfl(es, 0);
            if (lane == 0) { mx_sh[ql] = mx; inv_sh[ql] = 1.0f / es; }
        }
    }
    __syncthreads();

    // tile compute + Cb write: thread = (ql = tid>>2, tc = tid&3)
    {
        const int ql = tid >> 2;
        const int tc = tid & 3;
        const float px = px_sh[ql], py = py_sh[ql];
        const float mx = mx_sh[ql], inv = inv_sh[ql];
        const float* lgq = &lg[ql * CC];
        float* cbrow = Cb + ((size_t)b * Q + q0 + ql) * T + tc * 32;
        #pragma unroll
        for (int k = 0; k < 8; ++k) {
            float4 o;
            #pragma unroll
            for (int e = 0; e < 4; ++e) {
                const int t = tc * 32 + 4 * k + e;
                const int labv = lab_sh[t];
                float prob = expf(lgq[labv] - mx) * inv;
                float cp   = fabsf(px - tx_sh[t]) + fabsf(py - ty_sh[t]);
                float val  = cp - prob;
                (&o.x)[e] = val;
                tile[t][ql] = val;
            }
            ((float4*)cbrow)[k] = o;
        }
    }
    __syncthreads();

    // CbT write + rowmin partials: thread = (rg = tid>>4, c4 = tid&15)
    {
        const int rg = tid >> 4;
        const int c4 = tid & 15;
        #pragma unroll
        for (int it = 0; it < 8; ++it) {
            const int t = it * 16 + rg;
            float4 v = *(const float4*)&tile[t][4 * c4];
            *(float4*)(CbT + ((size_t)b * NR + t) * Q + q0 + 4 * c4) = v;

            unsigned long long bk = ~0ull;
            const float* vf = (const float*)&v;
            #pragma unroll
            for (int e = 0; e < 4; ++e) {
                unsigned bits = __float_as_uint(vf[e]);
                unsigned mono = (bits & 0x80000000u) ? ~bits
                                                     : (bits | 0x80000000u);
                const int j = q0 + 4 * c4 + e;
                unsigned long long key =
                    ((unsigned long long)mono << 10) | (unsigned)j;
                bk = (key < bk) ? key : bk;
            }
            #pragma unroll
            for (int off = 1; off < 16; off <<= 1) {
                unsigned long long ok = __shfl_xor(bk, off);
                bk = (ok < bk) ? ok : bk;
            }
            if (c4 == 0) part[((size_t)b * NR + t) * NQB + qb] = bk;
        }
    }
}

// ---------------------------------------------------------------------------
// Fallback cost kernel (only used if workspace is too small).
// ---------------------------------------------------------------------------
__global__ __launch_bounds__(256) void cost_kernel(
    const float* __restrict__ logits, const float* __restrict__ ppts,
    const int* __restrict__ tlab, const float* __restrict__ tpts,
    float* __restrict__ Cb)
{
    const int blk  = blockIdx.x;
    const int b    = blk >> 8;
    const int wave = threadIdx.x >> 6;
    const int lane = threadIdx.x & 63;
    const int q    = (blk & 255) * 4 + wave;

    __shared__ float tx_sh[T], ty_sh[T];
    __shared__ int   lab_sh[T];
    __shared__ float logit_sh[4][CC];

    if (threadIdx.x < T) {
        lab_sh[threadIdx.x] = tlab[b * T + threadIdx.x];
        tx_sh[threadIdx.x]  = tpts[(b * T + threadIdx.x) * 2 + 0];
        ty_sh[threadIdx.x]  = tpts[(b * T + threadIdx.x) * 2 + 1];
    }
    const float* lrow = logits + ((size_t)b * Q + q) * CC;
    float l0 = lrow[lane];
    float l1 = (lane + 64 < CC) ? lrow[lane + 64] : -INFINITY;
    logit_sh[wave][lane] = l0;
    if (lane + 64 < CC) logit_sh[wave][lane + 64] = l1;

    float mx = fmaxf(l0, l1);
    #pragma unroll
    for (int off = 32; off > 0; off >>= 1) mx = fmaxf(mx, __shfl_down(mx, off));
    mx = __shfl(mx, 0);
    float es = expf(l0 - mx) + ((lane + 64 < CC) ? expf(l1 - mx) : 0.0f);
    #pragma unroll
    for (int off = 32; off > 0; off >>= 1) es += __shfl_down(es, off);
    es = __shfl(es, 0);
    const float inv = 1.0f / es;
    const float px = ppts[((size_t)b * Q + q) * 2 + 0];
    const float py = ppts[((size_t)b * Q + q) * 2 + 1];
    __syncthreads();
    float* outrow = Cb + ((size_t)b * Q + q) * T;
    #pragma unroll
    for (int t = lane; t < T; t += 64) {
        int   labv = lab_sh[t];
        float prob = expf(logit_sh[wave][labv] - mx) * inv;
        float cp   = fabsf(px - tx_sh[t]) + fabsf(py - ty_sh[t]);
        outrow[t]  = cp - prob;
    }
}

// DPP wave64 umin reduce step: dest = min(x, x shifted by ctrl); OOB lanes
// keep old (= x), so they're no-ops. ctrl is a compile-time constant.
#define DPP_UMIN_STEP(x, ctrl)                                              \
    {                                                                       \
        unsigned _t = (unsigned)__builtin_amdgcn_update_dpp(                \
            (int)(x), (int)(x), (ctrl), 0xF, 0xF, false);                   \
        (x) = ((x) < _t) ? (x) : _t;                                        \
    }

// ---------------------------------------------------------------------------
// Kernel 2: JV solver. ONE WAVE per batch. fp32 duals/dists; DPP argmin.
// Lane L owns columns j = 256*g + 4*L + e  (g=0..3, e=0..3, k = 4g+e).
// Greedy init from prep's partial rowmin keys, then fp32 shortest augmenting
// path (scipy variant) for leftover rows. Argmin: monotone-u32 encode ->
// 6-step DPP umin (VALU-only) -> ballot + readlane (no LDS in the chain).
// ---------------------------------------------------------------------------
template<int USET>
__global__ __launch_bounds__(64) void solve_kernel(
    const float* __restrict__ Cb,    // [BS][Q][T] fallback (strided)
    const float* __restrict__ CbT,   // [BS][NR][Q] row-major solver cost
    const unsigned long long* __restrict__ part,  // [BS][NR][NQB] or nullptr
    float* __restrict__ out_rows,    // [BS][T]
    float* __restrict__ out_cols)    // [BS][T]
{
    const int b    = blockIdx.x;
    const int lane = threadIdx.x;    // 0..63

    __shared__ int    row4col[M];    // col j -> row (-1 free)
    __shared__ int    col4row[NR];   // row i -> col (-1 free)
    __shared__ float  u_sh[NR];
    __shared__ int    path_lds[M];   // swizzled: A(j) = 256g + 64e + L
    __shared__ int    SRr[NR];       // rows that joined SR (excl. curRow)
    __shared__ float  SRd[NR];       // dist at which they joined
    __shared__ int    minj_sh[NR];   // greedy: per-row argmin column

    const float* CbB  = Cb  + (size_t)b * Q * T;
    const float* CbTB = CbT + (size_t)b * NR * Q;

    for (int j = lane; j < M;  j += 64) row4col[j] = -1;
    for (int i = lane; i < NR; i += 64) col4row[i] = -1;

    // reduce prep's partial keys -> u duals + greedy argmin columns
    if (part) {
        for (int r = lane; r < NR; r += 64) {
            const unsigned long long* pr = part + ((size_t)b * NR + r) * NQB;
            unsigned long long k = pr[0];
            #pragma unroll
            for (int i = 1; i < NQB; ++i) {
                unsigned long long o = pr[i];
                k = (o < k) ? o : k;
            }
            minj_sh[r] = (int)(k & 1023u);
            unsigned mono = (unsigned)(k >> 10);
            unsigned bits = (mono & 0x80000000u) ? (mono ^ 0x80000000u) : ~mono;
            u_sh[r] = __uint_as_float(bits);
        }
    } else {
        for (int i = lane; i < NR; i += 64) { minj_sh[i] = -1; u_sh[i] = 0.0f; }
    }
    __syncthreads();

    // greedy first-come-first-served assignment
    if (part) {
        for (int i = lane; i < NR; i += 64) {
            const int mj = minj_sh[i];
            int first = -1;
            for (int t2 = 0; t2 < NR; ++t2)
                if (first < 0 && minj_sh[t2] == mj) first = t2;
            if (first == i) { col4row[i] = mj; row4col[mj] = i; }
        }
        __syncthreads();
    }

    const float FINF = INFINITY;
    float v_[16], dist_[16];
    #pragma unroll
    for (int k = 0; k < 16; ++k) v_[k] = 0.0f;

    for (int curRow = 0; curRow < NR; ++curRow) {
        if (col4row[curRow] >= 0) continue;            // greedy got it

        #pragma unroll
        for (int k = 0; k < 16; ++k) dist_[k] = FINF;
        unsigned used  = 0;          // SC bitmask, bit k
        float    minVal = 0.0f;
        int      i_s  = curRow;
        int      sink = -1;
        int      cnt  = 0;

        for (int guard = 0; guard <= M; ++guard) {
            const float ui = u_sh[i_s];
            const float s  = minVal - ui;

            float4 c4[4];
            if (USET) {
                const float4* row = (const float4*)(CbTB + (size_t)i_s * Q);
                #pragma unroll
                for (int g = 0; g < 4; ++g) c4[g] = row[lane + 64 * g];
            } else {
                const float* col = CbB + i_s;
                #pragma unroll
                for (int g = 0; g < 4; ++g) {
                    float* cf = (float*)&c4[g];
                    #pragma unroll
                    for (int e = 0; e < 4; ++e)
                        cf[e] = col[(size_t)(256 * g + 4 * lane + e) * T];
                }
            }

            // relax free columns + per-lane argmin (ascending j within lane)
            float lmin = FINF; int lidx = 0;
            #pragma unroll
            for (int g = 0; g < 4; ++g) {
                const float* cf = (const float*)&c4[g];
                #pragma unroll
                for (int e = 0; e < 4; ++e) {
                    const int k = 4 * g + e;
                    const int j = 256 * g + 4 * lane + e;
                    const bool fr = ((used >> k) & 1u) == 0u;
                    float r = s + cf[e] - v_[k];
                    if (fr && r < dist_[k]) {
                        dist_[k] = r;
                        path_lds[256 * g + 64 * e + lane] = i_s;  // swizzled
                    }
                    float a = fr ? dist_[k] : FINF;
                    if (a < lmin) { lmin = a; lidx = j; }
                }
            }

            // speculative owner lookup (hides row4col LDS latency)
            const int cand = row4col[lidx];

            // monotone encode fp32 -> u32 (order-preserving)
            unsigned bits  = __float_as_uint(lmin);
            unsigned lmono = (bits & 0x80000000u) ? ~bits : (bits | 0x80000000u);

            // wave64 min-reduce, VALU-only DPP (result accumulates in lane 63)
            unsigned rmin = lmono;
            DPP_UMIN_STEP(rmin, 0x111);   // row_shr:1
            DPP_UMIN_STEP(rmin, 0x112);   // row_shr:2
            DPP_UMIN_STEP(rmin, 0x114);   // row_shr:4
            DPP_UMIN_STEP(rmin, 0x118);   // row_shr:8
            DPP_UMIN_STEP(rmin, 0x142);   // row_bcast:15
            DPP_UMIN_STEP(rmin, 0x143);   // row_bcast:31
            const unsigned gmin = (unsigned)__builtin_amdgcn_readlane((int)rmin, 63);

            // locate winner lane (lowest lane on exact ties; ties measure-0)
            const unsigned long long bmask = __ballot(lmono == gmin);
            const int winner = __ffsll(bmask) - 1;

            minVal = __uint_as_float(
                (unsigned)__builtin_amdgcn_readlane((int)__float_as_uint(lmin),
                                                    winner));
            const int jstar = __builtin_amdgcn_readlane(lidx, winner);

            if (((jstar >> 2) & 63) == lane)
                used |= (1u << (((jstar >> 8) << 2) | (jstar & 3)));

            const int ra = __builtin_amdgcn_readlane(cand, winner);
            if (ra == -1) { sink = jstar; break; }
            if (lane == 0 && cnt < NR) { SRr[cnt] = ra; SRd[cnt] = minVal; }
            cnt++;
            i_s = ra;
        }

        // dual updates (scipy style, out of loop)
        #pragma unroll
        for (int k = 0; k < 16; ++k)
            if ((used >> k) & 1u) v_[k] += dist_[k] - minVal;

        if (lane == 0) u_sh[curRow] += minVal;
        for (int t = lane; t < cnt; t += 64)
            u_sh[SRr[t]] += minVal - SRd[t];

        // augment along path (serial, lane 0)
        if (lane == 0) {
            int j = sink;
            for (int g2 = 0; g2 < NR + 2; ++g2) {
                int pi = path_lds[((j >> 8) << 8) | ((j & 3) << 6) |
                                  ((j >> 2) & 63)];
                row4col[j] = pi;
                int jn = col4row[pi];
                col4row[pi] = j;
                if (pi == curRow) break;
                j = jn;
            }
        }
        __syncthreads();
    }

    // outputs: row_idx = sorted q, col_idx = matching t
    for (int t = lane; t < NR; t += 64) {
        int q = col4row[t];
        int rank = 0;
        for (int t2 = 0; t2 < NR; ++t2) rank += (col4row[t2] < q);
        out_rows[b * NR + rank] = (float)q;
        out_cols[b * NR + rank] = (float)t;
    }
}

// ---------------------------------------------------------------------------
extern "C" void kernel_launch(void* const* d_in, const int* in_sizes, int n_in,
                              void* d_out, int out_size, void* d_ws, size_t ws_size,
                              hipStream_t stream) {
    const float* logits = (const float*)d_in[0];
    const float* ppts   = (const float*)d_in[1];
    const int*   tlab   = (const int*)  d_in[2];
    const float* tpts   = (const float*)d_in[3];

    float* Cb   = (float*)d_out;                 // BS*Q*T floats
    float* rows = Cb + (size_t)BS * Q * T;       // BS*T floats
    float* cols = rows + (size_t)BS * T;         // BS*T floats

    float* CbT = (float*)d_ws;                               // 8 MiB
    unsigned long long* part =
        (unsigned long long*)((char*)d_ws + (size_t)BS * NR * Q * sizeof(float));

    const size_t need = (size_t)BS * NR * Q * sizeof(float)
                      + (size_t)BS * NR * NQB * sizeof(unsigned long long);

    if (ws_size >= need) {
        prep_kernel<<<BS * NQB, 256, 0, stream>>>(logits, ppts, tlab, tpts,
                                                  Cb, CbT, part);
        solve_kernel<1><<<BS, 64, 0, stream>>>(Cb, CbT, part, rows, cols);
    } else {
        cost_kernel<<<4096, 256, 0, stream>>>(logits, ppts, tlab, tpts, Cb);
        solve_kernel<0><<<BS, 64, 0, stream>>>(Cb, CbT, nullptr, rows, cols);
    }
}

// Round 8
// 131.012 us; speedup vs baseline: 1.2770x; 1.1346x over previous
//
#include <hip/hip_runtime.h>
#include <hip/hip_bf16.h>
#include <math.h>

#define BS 16
#define Q 1024
#define CC 92
#define T 128
#define M 1024   // columns in transposed problem (= Q)
#define NR 128   // rows in transposed problem (= T)
#define NQB 16   // q-blocks of 64 per batch

// ---------------------------------------------------------------------------
// Fused prep kernel: one block per (b, 64-q slab). Bit-identical Cb.
// Emits per-(row t, qblock) partial ROWMIN keys (R5/R6 semantics — the
// colmin init of R7 was dual-infeasible for the rectangular problem).
// part layout: [b][qb][t]  (solver reads lane-consecutive in t -> coalesced)
// ---------------------------------------------------------------------------
__global__ __launch_bounds__(256) void prep_kernel(
    const float* __restrict__ logits,   // [BS][Q][CC]
    const float* __restrict__ ppts,     // [BS][Q][2]
    const int*   __restrict__ tlab,     // [BS][T]
    const float* __restrict__ tpts,     // [BS][T][2]
    float* __restrict__ Cb,             // [BS][Q][T]
    float* __restrict__ CbT,            // [BS][NR][Q]
    unsigned long long* __restrict__ part)  // [BS][NQB][NR]
{
    const int blk = blockIdx.x;         // 0..BS*NQB-1
    const int b   = blk >> 4;
    const int qb  = blk & 15;
    const int q0  = qb * 64;
    const int tid = threadIdx.x;
    const int lane = tid & 63;

    __shared__ float lg[64 * CC];       // logits slab, [ql][c]
    __shared__ float tile[128][68];     // [t][ql], pitch 68 for b128 align
    __shared__ float tx_sh[T], ty_sh[T];
    __shared__ int   lab_sh[T];
    __shared__ float mx_sh[64], inv_sh[64], px_sh[64], py_sh[64];

    if (tid < T) {
        lab_sh[tid] = tlab[b * T + tid];
        tx_sh[tid]  = tpts[(b * T + tid) * 2 + 0];
        ty_sh[tid]  = tpts[(b * T + tid) * 2 + 1];
    }
    if (tid < 64) {
        px_sh[tid] = ppts[((size_t)b * Q + q0 + tid) * 2 + 0];
        py_sh[tid] = ppts[((size_t)b * Q + q0 + tid) * 2 + 1];
    }
    const float* lbase = logits + ((size_t)b * Q + q0) * CC;
    for (int idx = tid; idx < 64 * CC; idx += 256) lg[idx] = lbase[idx];
    __syncthreads();

    // softmax stats: EXACT same op sequence as original cost kernel.
    {
        const int w = tid >> 6;
        for (int s = 0; s < 16; ++s) {
            const int ql = w * 16 + s;
            const float* c = &lg[ql * CC];
            float l0 = c[lane];
            float l1 = (lane + 64 < CC) ? c[lane + 64] : -INFINITY;
            float mx = fmaxf(l0, l1);
            #pragma unroll
            for (int off = 32; off > 0; off >>= 1)
                mx = fmaxf(mx, __shfl_down(mx, off));
            mx = __shfl(mx, 0);
            float es = expf(l0 - mx) + ((lane + 64 < CC) ? expf(l1 - mx) : 0.0f);
            #pragma unroll
            for (int off = 32; off > 0; off >>= 1) es += __shfl_down(es, off);
            es = __shfl(es, 0);
            if (lane == 0) { mx_sh[ql] = mx; inv_sh[ql] = 1.0f / es; }
        }
    }
    __syncthreads();

    // tile compute + Cb write: thread = (ql = tid>>2, tc = tid&3)
    {
        const int ql = tid >> 2;
        const int tc = tid & 3;
        const float px = px_sh[ql], py = py_sh[ql];
        const float mx = mx_sh[ql], inv = inv_sh[ql];
        const float* lgq = &lg[ql * CC];
        float* cbrow = Cb + ((size_t)b * Q + q0 + ql) * T + tc * 32;
        #pragma unroll
        for (int k = 0; k < 8; ++k) {
            float4 o;
            #pragma unroll
            for (int e = 0; e < 4; ++e) {
                const int t = tc * 32 + 4 * k + e;
                const int labv = lab_sh[t];
                float prob = expf(lgq[labv] - mx) * inv;
                float cp   = fabsf(px - tx_sh[t]) + fabsf(py - ty_sh[t]);
                float val  = cp - prob;
                (&o.x)[e] = val;
                tile[t][ql] = val;
            }
            ((float4*)cbrow)[k] = o;
        }
    }
    __syncthreads();

    // CbT write + rowmin partials: thread = (rg = tid>>4, c4 = tid&15)
    {
        const int rg = tid >> 4;
        const int c4 = tid & 15;
        #pragma unroll
        for (int it = 0; it < 8; ++it) {
            const int t = it * 16 + rg;
            float4 v = *(const float4*)&tile[t][4 * c4];
            *(float4*)(CbT + ((size_t)b * NR + t) * Q + q0 + 4 * c4) = v;

            unsigned long long bk = ~0ull;
            const float* vf = (const float*)&v;
            #pragma unroll
            for (int e = 0; e < 4; ++e) {
                unsigned bits = __float_as_uint(vf[e]);
                unsigned mono = (bits & 0x80000000u) ? ~bits
                                                     : (bits | 0x80000000u);
                const int j = q0 + 4 * c4 + e;
                unsigned long long key =
                    ((unsigned long long)mono << 10) | (unsigned)j;
                bk = (key < bk) ? key : bk;
            }
            #pragma unroll
            for (int off = 1; off < 16; off <<= 1) {
                unsigned long long ok = __shfl_xor(bk, off);
                bk = (ok < bk) ? ok : bk;
            }
            if (c4 == 0) part[((size_t)b * NQB + qb) * NR + t] = bk;
        }
    }
}

// ---------------------------------------------------------------------------
// Fallback cost kernel (only used if workspace is too small).
// ---------------------------------------------------------------------------
__global__ __launch_bounds__(256) void cost_kernel(
    const float* __restrict__ logits, const float* __restrict__ ppts,
    const int* __restrict__ tlab, const float* __restrict__ tpts,
    float* __restrict__ Cb)
{
    const int blk  = blockIdx.x;
    const int b    = blk >> 8;
    const int wave = threadIdx.x >> 6;
    const int lane = threadIdx.x & 63;
    const int q    = (blk & 255) * 4 + wave;

    __shared__ float tx_sh[T], ty_sh[T];
    __shared__ int   lab_sh[T];
    __shared__ float logit_sh[4][CC];

    if (threadIdx.x < T) {
        lab_sh[threadIdx.x] = tlab[b * T + threadIdx.x];
        tx_sh[threadIdx.x]  = tpts[(b * T + threadIdx.x) * 2 + 0];
        ty_sh[threadIdx.x]  = tpts[(b * T + threadIdx.x) * 2 + 1];
    }
    const float* lrow = logits + ((size_t)b * Q + q) * CC;
    float l0 = lrow[lane];
    float l1 = (lane + 64 < CC) ? lrow[lane + 64] : -INFINITY;
    logit_sh[wave][lane] = l0;
    if (lane + 64 < CC) logit_sh[wave][lane + 64] = l1;

    float mx = fmaxf(l0, l1);
    #pragma unroll
    for (int off = 32; off > 0; off >>= 1) mx = fmaxf(mx, __shfl_down(mx, off));
    mx = __shfl(mx, 0);
    float es = expf(l0 - mx) + ((lane + 64 < CC) ? expf(l1 - mx) : 0.0f);
    #pragma unroll
    for (int off = 32; off > 0; off >>= 1) es += __shfl_down(es, off);
    es = __shfl(es, 0);
    const float inv = 1.0f / es;
    const float px = ppts[((size_t)b * Q + q) * 2 + 0];
    const float py = ppts[((size_t)b * Q + q) * 2 + 1];
    __syncthreads();
    float* outrow = Cb + ((size_t)b * Q + q) * T;
    #pragma unroll
    for (int t = lane; t < T; t += 64) {
        int   labv = lab_sh[t];
        float prob = expf(logit_sh[wave][labv] - mx) * inv;
        float cp   = fabsf(px - tx_sh[t]) + fabsf(py - ty_sh[t]);
        outrow[t]  = cp - prob;
    }
}

// DPP wave64 umin reduce step: dest = min(x, x shifted by ctrl); OOB lanes
// keep old (= x), so they're no-ops. ctrl is a compile-time constant.
#define DPP_UMIN_STEP(x, ctrl)                                              \
    {                                                                       \
        unsigned _t = (unsigned)__builtin_amdgcn_update_dpp(                \
            (int)(x), (int)(x), (ctrl), 0xF, 0xF, false);                   \
        (x) = ((x) < _t) ? (x) : _t;                                        \
    }

// ---------------------------------------------------------------------------
// Kernel 2: JV solver. ONE WAVE per batch.
// Init = R6 rowmin-greedy (u[i]=rowmin, v=0 -> dual-feasible for the
// rectangular problem; R7's colmin-v>0 init was infeasible). Greedy winner
// via LDS atomicMin; leftover rows iterated from a ballot bitmask; fp32
// Dijkstra body IDENTICAL to R6 (passed bit-exact). Output via ballot-rank.
// ---------------------------------------------------------------------------
template<int USET>
__global__ __launch_bounds__(64) void solve_kernel(
    const float* __restrict__ Cb,    // [BS][Q][T] fallback (strided)
    const float* __restrict__ CbT,   // [BS][NR][Q] row-major solver cost
    const unsigned long long* __restrict__ part,  // [BS][NQB][NR] or nullptr
    float* __restrict__ out_rows,    // [BS][T]
    float* __restrict__ out_cols)    // [BS][T]
{
    const int b    = blockIdx.x;
    const int lane = threadIdx.x;    // 0..63

    __shared__ int    row4col[M];    // col j -> row (-1 free)
    __shared__ int    col4row[NR];   // row i -> col (-1 free)
    __shared__ float  u_sh[NR];
    __shared__ int    path_lds[M];   // swizzled: A(j) = 256g + 64e + L
    __shared__ int    SRr[NR];       // rows that joined SR (excl. curRow)
    __shared__ float  SRd[NR];       // dist at which they joined
    __shared__ int    minj_sh[NR];   // per-row argmin column
    __shared__ int    claim[M];      // col j -> lowest row claiming it

    const float* CbB  = Cb  + (size_t)b * Q * T;
    const float* CbTB = CbT + (size_t)b * NR * Q;

    for (int j = lane; j < M;  j += 64) { row4col[j] = -1; claim[j] = 0x7fffffff; }
    for (int i = lane; i < NR; i += 64) col4row[i] = -1;

    // decode rowmin partials (coalesced: lane-consecutive in r)
    if (part) {
        #pragma unroll
        for (int r2 = 0; r2 < 2; ++r2) {
            const int r = lane + 64 * r2;
            const unsigned long long* pr = part + (size_t)b * NQB * NR + r;
            unsigned long long k = pr[0];
            #pragma unroll
            for (int i = 1; i < NQB; ++i) {
                unsigned long long o = pr[(size_t)i * NR];
                k = (o < k) ? o : k;
            }
            minj_sh[r] = (int)(k & 1023u);
            unsigned mono = (unsigned)(k >> 10);
            unsigned bits = (mono & 0x80000000u) ? (mono ^ 0x80000000u) : ~mono;
            u_sh[r] = __uint_as_float(bits);
        }
    } else {
        for (int i = lane; i < NR; i += 64) { minj_sh[i] = -1; u_sh[i] = 0.0f; }
    }
    __syncthreads();

    // greedy: lowest row index wins its argmin column (== R6 first-occurrence)
    if (part) {
        #pragma unroll
        for (int r2 = 0; r2 < 2; ++r2) {
            const int r = lane + 64 * r2;
            atomicMin(&claim[minj_sh[r]], r);
        }
        __syncthreads();
        #pragma unroll
        for (int r2 = 0; r2 < 2; ++r2) {
            const int r = lane + 64 * r2;
            const int mj = minj_sh[r];
            if (claim[mj] == r) { col4row[r] = mj; row4col[mj] = r; }
        }
        __syncthreads();
    }

    // unmatched-row bitmasks (ascending order == R6 trajectory)
    unsigned long long um0 = ~__ballot(col4row[lane] >= 0);
    unsigned long long um1 = ~__ballot(col4row[lane + 64] >= 0);

    const float FINF = INFINITY;
    float v_[16], dist_[16];
    #pragma unroll
    for (int k = 0; k < 16; ++k) v_[k] = 0.0f;

    for (int half = 0; half < 2; ++half) {
        unsigned long long mask = half ? um1 : um0;
        while (mask) {
            const int curRow = __ffsll(mask) - 1 + 64 * half;
            mask &= mask - 1;

            #pragma unroll
            for (int k = 0; k < 16; ++k) dist_[k] = FINF;
            unsigned used  = 0;          // SC bitmask, bit k
            float    minVal = 0.0f;
            int      i_s  = curRow;
            int      sink = -1;
            int      cnt  = 0;

            for (int guard = 0; guard <= M; ++guard) {
                const float ui = u_sh[i_s];
                const float s  = minVal - ui;

                float4 c4[4];
                if (USET) {
                    const float4* row = (const float4*)(CbTB + (size_t)i_s * Q);
                    #pragma unroll
                    for (int g = 0; g < 4; ++g) c4[g] = row[lane + 64 * g];
                } else {
                    const float* col = CbB + i_s;
                    #pragma unroll
                    for (int g = 0; g < 4; ++g) {
                        float* cf = (float*)&c4[g];
                        #pragma unroll
                        for (int e = 0; e < 4; ++e)
                            cf[e] = col[(size_t)(256 * g + 4 * lane + e) * T];
                    }
                }

                // relax free columns + per-lane argmin
                float lmin = FINF; int lidx = 0;
                #pragma unroll
                for (int g = 0; g < 4; ++g) {
                    const float* cf = (const float*)&c4[g];
                    #pragma unroll
                    for (int e = 0; e < 4; ++e) {
                        const int k = 4 * g + e;
                        const int j = 256 * g + 4 * lane + e;
                        const bool fr = ((used >> k) & 1u) == 0u;
                        float r = s + cf[e] - v_[k];
                        if (fr && r < dist_[k]) {
                            dist_[k] = r;
                            path_lds[256 * g + 64 * e + lane] = i_s;  // swizzled
                        }
                        float a = fr ? dist_[k] : FINF;
                        if (a < lmin) { lmin = a; lidx = j; }
                    }
                }

                // speculative owner lookup (hides row4col LDS latency)
                const int cand = row4col[lidx];

                // monotone encode fp32 -> u32 (order-preserving)
                unsigned bits  = __float_as_uint(lmin);
                unsigned lmono = (bits & 0x80000000u) ? ~bits
                                                      : (bits | 0x80000000u);

                // wave64 min-reduce, VALU-only DPP (accumulates in lane 63)
                unsigned rmin = lmono;
                DPP_UMIN_STEP(rmin, 0x111);   // row_shr:1
                DPP_UMIN_STEP(rmin, 0x112);   // row_shr:2
                DPP_UMIN_STEP(rmin, 0x114);   // row_shr:4
                DPP_UMIN_STEP(rmin, 0x118);   // row_shr:8
                DPP_UMIN_STEP(rmin, 0x142);   // row_bcast:15
                DPP_UMIN_STEP(rmin, 0x143);   // row_bcast:31
                const unsigned gmin =
                    (unsigned)__builtin_amdgcn_readlane((int)rmin, 63);

                // winner lane (lowest lane on exact ties; ties measure-0)
                const unsigned long long bmask = __ballot(lmono == gmin);
                const int winner = __ffsll(bmask) - 1;

                minVal = __uint_as_float(
                    (unsigned)__builtin_amdgcn_readlane(
                        (int)__float_as_uint(lmin), winner));
                const int jstar = __builtin_amdgcn_readlane(lidx, winner);

                if (((jstar >> 2) & 63) == lane)
                    used |= (1u << (((jstar >> 8) << 2) | (jstar & 3)));

                const int ra = __builtin_amdgcn_readlane(cand, winner);
                if (ra == -1) { sink = jstar; break; }
                if (lane == 0 && cnt < NR) { SRr[cnt] = ra; SRd[cnt] = minVal; }
                cnt++;
                i_s = ra;
            }

            // dual updates (scipy style, out of loop)
            #pragma unroll
            for (int k = 0; k < 16; ++k)
                if ((used >> k) & 1u) v_[k] += dist_[k] - minVal;

            if (lane == 0) u_sh[curRow] += minVal;
            for (int t = lane; t < cnt; t += 64)
                u_sh[SRr[t]] += minVal - SRd[t];

            // augment along path (serial, lane 0)
            if (lane == 0) {
                int j = sink;
                for (int g2 = 0; g2 < NR + 2; ++g2) {
                    int pi = path_lds[((j >> 8) << 8) | ((j & 3) << 6) |
                                      ((j >> 2) & 63)];
                    row4col[j] = pi;
                    int jn = col4row[pi];
                    col4row[pi] = j;
                    if (pi == curRow) break;
                    j = jn;
                }
            }
            __syncthreads();
        }
    }

    // output: rank(j) = #matched j' < j, via ballot prefix counts.
    // matched columns ascending j == matched q ascending == reference order.
    int base = 0;
    #pragma unroll
    for (int g = 0; g < 4; ++g) {
        int tv[4], mt[4];
        #pragma unroll
        for (int e = 0; e < 4; ++e) {
            const int j = 256 * g + 4 * lane + e;
            tv[e] = row4col[j];
            mt[e] = (tv[e] >= 0);
        }
        unsigned long long B[4];
        #pragma unroll
        for (int e = 0; e < 4; ++e) B[e] = __ballot(mt[e] != 0);
        const unsigned long long low = (1ull << lane) - 1ull;
        int below = base;
        #pragma unroll
        for (int e = 0; e < 4; ++e) below += __popcll(B[e] & low);
        int local = 0;
        #pragma unroll
        for (int e = 0; e < 4; ++e) {
            if (mt[e]) {
                const int rank = below + local;
                const int j = 256 * g + 4 * lane + e;
                out_rows[b * NR + rank] = (float)j;
                out_cols[b * NR + rank] = (float)tv[e];
                ++local;
            }
        }
        #pragma unroll
        for (int e = 0; e < 4; ++e) base += __popcll(B[e]);
    }
}

// ---------------------------------------------------------------------------
extern "C" void kernel_launch(void* const* d_in, const int* in_sizes, int n_in,
                              void* d_out, int out_size, void* d_ws, size_t ws_size,
                              hipStream_t stream) {
    const float* logits = (const float*)d_in[0];
    const float* ppts   = (const float*)d_in[1];
    const int*   tlab   = (const int*)  d_in[2];
    const float* tpts   = (const float*)d_in[3];

    float* Cb   = (float*)d_out;                 // BS*Q*T floats
    float* rows = Cb + (size_t)BS * Q * T;       // BS*T floats
    float* cols = rows + (size_t)BS * T;         // BS*T floats

    float* CbT = (float*)d_ws;                               // 8 MiB
    unsigned long long* part =
        (unsigned long long*)((char*)d_ws + (size_t)BS * NR * Q * sizeof(float));

    const size_t need = (size_t)BS * NR * Q * sizeof(float)
                      + (size_t)BS * NQB * NR * sizeof(unsigned long long);

    if (ws_size >= need) {
        prep_kernel<<<BS * NQB, 256, 0, stream>>>(logits, ppts, tlab, tpts,
                                                  Cb, CbT, part);
        solve_kernel<1><<<BS, 64, 0, stream>>>(Cb, CbT, part, rows, cols);
    } else {
        cost_kernel<<<4096, 256, 0, stream>>>(logits, ppts, tlab, tpts, Cb);
        solve_kernel<0><<<BS, 64, 0, stream>>>(Cb, CbT, nullptr, rows, cols);
    }
}

// Round 9
// 127.713 us; speedup vs baseline: 1.3100x; 1.0258x over previous
//
#include <hip/hip_runtime.h>
#include <hip/hip_bf16.h>
#include <math.h>

#define BS 16
#define Q 1024
#define CC 92
#define T 128
#define M 1024   // columns in transposed problem (= Q)
#define NR 128   // rows in transposed problem (= T)
#define NQB 16   // q-blocks of 64 per batch

// ---------------------------------------------------------------------------
// Fused prep kernel: one block per (b, 64-q slab). Bit-identical Cb.
// Grid decode XCD-swizzled: blk = qb*BS + b, so all 16 blocks of batch b
// share blk%8 == b%8 -> batch slab stays in one XCD's L2 for the solver
// (round-robin block->XCD heuristic; perf-only, never correctness).
// ---------------------------------------------------------------------------
__global__ __launch_bounds__(256) void prep_kernel(
    const float* __restrict__ logits,   // [BS][Q][CC]
    const float* __restrict__ ppts,     // [BS][Q][2]
    const int*   __restrict__ tlab,     // [BS][T]
    const float* __restrict__ tpts,     // [BS][T][2]
    float* __restrict__ Cb,             // [BS][Q][T]
    float* __restrict__ CbT,            // [BS][NR][Q]
    unsigned long long* __restrict__ part)  // [BS][NQB][NR]
{
    const int blk = blockIdx.x;         // 0..BS*NQB-1
    const int b   = blk & 15;           // XCD swizzle: blk%8 == b%8
    const int qb  = blk >> 4;
    const int q0  = qb * 64;
    const int tid = threadIdx.x;
    const int lane = tid & 63;

    __shared__ float lg[64 * CC];       // logits slab, [ql][c]
    __shared__ float tile[128][68];     // [t][ql], pitch 68 for b128 align
    __shared__ float tx_sh[T], ty_sh[T];
    __shared__ int   lab_sh[T];
    __shared__ float mx_sh[64], inv_sh[64], px_sh[64], py_sh[64];

    if (tid < T) {
        lab_sh[tid] = tlab[b * T + tid];
        tx_sh[tid]  = tpts[(b * T + tid) * 2 + 0];
        ty_sh[tid]  = tpts[(b * T + tid) * 2 + 1];
    }
    if (tid < 64) {
        px_sh[tid] = ppts[((size_t)b * Q + q0 + tid) * 2 + 0];
        py_sh[tid] = ppts[((size_t)b * Q + q0 + tid) * 2 + 1];
    }
    const float* lbase = logits + ((size_t)b * Q + q0) * CC;
    for (int idx = tid; idx < 64 * CC; idx += 256) lg[idx] = lbase[idx];
    __syncthreads();

    // softmax stats: EXACT same op sequence as original cost kernel.
    {
        const int w = tid >> 6;
        for (int s = 0; s < 16; ++s) {
            const int ql = w * 16 + s;
            const float* c = &lg[ql * CC];
            float l0 = c[lane];
            float l1 = (lane + 64 < CC) ? c[lane + 64] : -INFINITY;
            float mx = fmaxf(l0, l1);
            #pragma unroll
            for (int off = 32; off > 0; off >>= 1)
                mx = fmaxf(mx, __shfl_down(mx, off));
            mx = __shfl(mx, 0);
            float es = expf(l0 - mx) + ((lane + 64 < CC) ? expf(l1 - mx) : 0.0f);
            #pragma unroll
            for (int off = 32; off > 0; off >>= 1) es += __shfl_down(es, off);
            es = __shfl(es, 0);
            if (lane == 0) { mx_sh[ql] = mx; inv_sh[ql] = 1.0f / es; }
        }
    }
    __syncthreads();

    // tile compute + Cb write: thread = (ql = tid>>2, tc = tid&3)
    {
        const int ql = tid >> 2;
        const int tc = tid & 3;
        const float px = px_sh[ql], py = py_sh[ql];
        const float mx = mx_sh[ql], inv = inv_sh[ql];
        const float* lgq = &lg[ql * CC];
        float* cbrow = Cb + ((size_t)b * Q + q0 + ql) * T + tc * 32;
        #pragma unroll
        for (int k = 0; k < 8; ++k) {
            float4 o;
            #pragma unroll
            for (int e = 0; e < 4; ++e) {
                const int t = tc * 32 + 4 * k + e;
                const int labv = lab_sh[t];
                float prob = expf(lgq[labv] - mx) * inv;
                float cp   = fabsf(px - tx_sh[t]) + fabsf(py - ty_sh[t]);
                float val  = cp - prob;
                (&o.x)[e] = val;
                tile[t][ql] = val;
            }
            ((float4*)cbrow)[k] = o;
        }
    }
    __syncthreads();

    // CbT write + rowmin partials: thread = (rg = tid>>4, c4 = tid&15)
    {
        const int rg = tid >> 4;
        const int c4 = tid & 15;
        #pragma unroll
        for (int it = 0; it < 8; ++it) {
            const int t = it * 16 + rg;
            float4 v = *(const float4*)&tile[t][4 * c4];
            *(float4*)(CbT + ((size_t)b * NR + t) * Q + q0 + 4 * c4) = v;

            unsigned long long bk = ~0ull;
            const float* vf = (const float*)&v;
            #pragma unroll
            for (int e = 0; e < 4; ++e) {
                unsigned bits = __float_as_uint(vf[e]);
                unsigned mono = (bits & 0x80000000u) ? ~bits
                                                     : (bits | 0x80000000u);
                const int j = q0 + 4 * c4 + e;
                unsigned long long key =
                    ((unsigned long long)mono << 10) | (unsigned)j;
                bk = (key < bk) ? key : bk;
            }
            #pragma unroll
            for (int off = 1; off < 16; off <<= 1) {
                unsigned long long ok = __shfl_xor(bk, off);
                bk = (ok < bk) ? ok : bk;
            }
            if (c4 == 0) part[((size_t)b * NQB + qb) * NR + t] = bk;
        }
    }
}

// ---------------------------------------------------------------------------
// Fallback cost kernel (only used if workspace is too small).
// ---------------------------------------------------------------------------
__global__ __launch_bounds__(256) void cost_kernel(
    const float* __restrict__ logits, const float* __restrict__ ppts,
    const int* __restrict__ tlab, const float* __restrict__ tpts,
    float* __restrict__ Cb)
{
    const int blk  = blockIdx.x;
    const int b    = blk >> 8;
    const int wave = threadIdx.x >> 6;
    const int lane = threadIdx.x & 63;
    const int q    = (blk & 255) * 4 + wave;

    __shared__ float tx_sh[T], ty_sh[T];
    __shared__ int   lab_sh[T];
    __shared__ float logit_sh[4][CC];

    if (threadIdx.x < T) {
        lab_sh[threadIdx.x] = tlab[b * T + threadIdx.x];
        tx_sh[threadIdx.x]  = tpts[(b * T + threadIdx.x) * 2 + 0];
        ty_sh[threadIdx.x]  = tpts[(b * T + threadIdx.x) * 2 + 1];
    }
    const float* lrow = logits + ((size_t)b * Q + q) * CC;
    float l0 = lrow[lane];
    float l1 = (lane + 64 < CC) ? lrow[lane + 64] : -INFINITY;
    logit_sh[wave][lane] = l0;
    if (lane + 64 < CC) logit_sh[wave][lane + 64] = l1;

    float mx = fmaxf(l0, l1);
    #pragma unroll
    for (int off = 32; off > 0; off >>= 1) mx = fmaxf(mx, __shfl_down(mx, off));
    mx = __shfl(mx, 0);
    float es = expf(l0 - mx) + ((lane + 64 < CC) ? expf(l1 - mx) : 0.0f);
    #pragma unroll
    for (int off = 32; off > 0; off >>= 1) es += __shfl_down(es, off);
    es = __shfl(es, 0);
    const float inv = 1.0f / es;
    const float px = ppts[((size_t)b * Q + q) * 2 + 0];
    const float py = ppts[((size_t)b * Q + q) * 2 + 1];
    __syncthreads();
    float* outrow = Cb + ((size_t)b * Q + q) * T;
    #pragma unroll
    for (int t = lane; t < T; t += 64) {
        int   labv = lab_sh[t];
        float prob = expf(logit_sh[wave][labv] - mx) * inv;
        float cp   = fabsf(px - tx_sh[t]) + fabsf(py - ty_sh[t]);
        outrow[t]  = cp - prob;
    }
}

// DPP wave64 umin reduce step: dest = min(x, x shifted by ctrl); OOB lanes
// keep old (= x), so they're no-ops. ctrl is a compile-time constant.
#define DPP_UMIN_STEP(x, ctrl)                                              \
    {                                                                       \
        unsigned _t = (unsigned)__builtin_amdgcn_update_dpp(                \
            (int)(x), (int)(x), (ctrl), 0xF, 0xF, false);                   \
        (x) = ((x) < _t) ? (x) : _t;                                        \
    }

#define DPP_UMIN_REDUCE(x)                                                  \
    DPP_UMIN_STEP(x, 0x111); DPP_UMIN_STEP(x, 0x112);                       \
    DPP_UMIN_STEP(x, 0x114); DPP_UMIN_STEP(x, 0x118);                       \
    DPP_UMIN_STEP(x, 0x142); DPP_UMIN_STEP(x, 0x143);

__device__ __forceinline__ unsigned mono_enc(float f) {
    unsigned b = __float_as_uint(f);
    return (b & 0x80000000u) ? ~b : (b | 0x80000000u);
}
__device__ __forceinline__ float mono_dec(unsigned m) {
    unsigned b = (m & 0x80000000u) ? (m ^ 0x80000000u) : ~m;
    return __uint_as_float(b);
}

// ---------------------------------------------------------------------------
// Kernel 2: JV solver. ONE WAVE per batch.
// Phase A: rowmin-greedy init (R6/R8, u[i]=rowmin, v=0 dual-feasible).
// Phase B: NEW — JV augmenting row reduction (ART): for each unmatched row,
//   scan reduced costs -> (m1,j1,m2); u[cur]+=m2, v[j1]-=(m2-m1) (feasible,
//   tight), steal j1; displaced row continues the chain; ends at free column.
//   Guard-bounded; leftovers go to Dijkstra, so correctness never depends on
//   ART termination.
// Phase C: fp32 Dijkstra, byte-identical to R8 (passed bit-exact).
// ---------------------------------------------------------------------------
template<int USET>
__global__ __launch_bounds__(64) void solve_kernel(
    const float* __restrict__ Cb,    // [BS][Q][T] fallback (strided)
    const float* __restrict__ CbT,   // [BS][NR][Q] row-major solver cost
    const unsigned long long* __restrict__ part,  // [BS][NQB][NR] or nullptr
    float* __restrict__ out_rows,    // [BS][T]
    float* __restrict__ out_cols)    // [BS][T]
{
    const int b    = blockIdx.x;
    const int lane = threadIdx.x;    // 0..63

    __shared__ int    row4col[M];    // col j -> row (-1 free)
    __shared__ int    col4row[NR];   // row i -> col (-1 free)
    __shared__ float  u_sh[NR];
    __shared__ int    path_lds[M];   // swizzled: A(j) = 256g + 64e + L
    __shared__ int    SRr[NR];       // rows that joined SR (excl. curRow)
    __shared__ float  SRd[NR];       // dist at which they joined
    __shared__ int    minj_sh[NR];   // per-row argmin column
    __shared__ int    claim[M];      // col j -> lowest row claiming it

    const float* CbB  = Cb  + (size_t)b * Q * T;
    const float* CbTB = CbT + (size_t)b * NR * Q;

    for (int j = lane; j < M;  j += 64) { row4col[j] = -1; claim[j] = 0x7fffffff; }
    for (int i = lane; i < NR; i += 64) col4row[i] = -1;

    // decode rowmin partials (coalesced: lane-consecutive in r)
    if (part) {
        #pragma unroll
        for (int r2 = 0; r2 < 2; ++r2) {
            const int r = lane + 64 * r2;
            const unsigned long long* pr = part + (size_t)b * NQB * NR + r;
            unsigned long long k = pr[0];
            #pragma unroll
            for (int i = 1; i < NQB; ++i) {
                unsigned long long o = pr[(size_t)i * NR];
                k = (o < k) ? o : k;
            }
            minj_sh[r] = (int)(k & 1023u);
            u_sh[r] = mono_dec((unsigned)(k >> 10));
        }
    } else {
        for (int i = lane; i < NR; i += 64) { minj_sh[i] = -1; u_sh[i] = 0.0f; }
    }
    __syncthreads();

    // greedy: lowest row index wins its argmin column
    if (part) {
        #pragma unroll
        for (int r2 = 0; r2 < 2; ++r2) {
            const int r = lane + 64 * r2;
            atomicMin(&claim[minj_sh[r]], r);
        }
        __syncthreads();
        #pragma unroll
        for (int r2 = 0; r2 < 2; ++r2) {
            const int r = lane + 64 * r2;
            const int mj = minj_sh[r];
            if (claim[mj] == r) { col4row[r] = mj; row4col[mj] = r; }
        }
        __syncthreads();
    }

    const float FINF = INFINITY;
    float v_[16], dist_[16];
    #pragma unroll
    for (int k = 0; k < 16; ++k) v_[k] = 0.0f;

    // ---------------- Phase B: augmenting row reduction ------------------
    {
        unsigned long long am0 = ~__ballot(col4row[lane] >= 0);
        unsigned long long am1 = ~__ballot(col4row[lane + 64] >= 0);
        for (int half = 0; half < 2; ++half) {
            unsigned long long mask = half ? am1 : am0;
            while (mask) {
                int cur = __ffsll(mask) - 1 + 64 * half;
                mask &= mask - 1;

                for (int step = 0; step < 48; ++step) {
                    const float ucur = u_sh[cur];

                    float4 c4[4];
                    if (USET) {
                        const float4* row =
                            (const float4*)(CbTB + (size_t)cur * Q);
                        #pragma unroll
                        for (int g = 0; g < 4; ++g) c4[g] = row[lane + 64 * g];
                    } else {
                        const float* col = CbB + cur;
                        #pragma unroll
                        for (int g = 0; g < 4; ++g) {
                            float* cf = (float*)&c4[g];
                            #pragma unroll
                            for (int e = 0; e < 4; ++e)
                                cf[e] = col[(size_t)(256*g + 4*lane + e) * T];
                        }
                    }

                    // per-lane (m1, j1) and m2 of reduced costs
                    float m1l = FINF, m2l = FINF; int j1l = 0;
                    #pragma unroll
                    for (int g = 0; g < 4; ++g) {
                        const float* cf = (const float*)&c4[g];
                        #pragma unroll
                        for (int e = 0; e < 4; ++e) {
                            const int k = 4 * g + e;
                            const int j = 256 * g + 4 * lane + e;
                            float r = cf[e] - ucur - v_[k];
                            if (r < m1l) { m2l = m1l; m1l = r; j1l = j; }
                            else if (r < m2l) { m2l = r; }
                        }
                    }

                    // global m1 via DPP
                    unsigned e1 = mono_enc(m1l);
                    unsigned r1 = e1;
                    DPP_UMIN_REDUCE(r1);
                    const unsigned g1 =
                        (unsigned)__builtin_amdgcn_readlane((int)r1, 63);
                    const unsigned long long bm = __ballot(e1 == g1);
                    const int winner = __ffsll(bm) - 1;
                    const int j1 = __builtin_amdgcn_readlane(j1l, winner);
                    const float m1 = mono_dec(g1);

                    // global m2 = min(winner's m2, others' m1)
                    unsigned e2 = mono_enc((lane == winner) ? m2l : m1l);
                    DPP_UMIN_REDUCE(e2);
                    const float m2 = mono_dec(
                        (unsigned)__builtin_amdgcn_readlane((int)e2, 63));

                    // dual update: u[cur] += m2 ; v[j1] -= (m2 - m1)
                    if (lane == 0) u_sh[cur] = ucur + m2;
                    if (((j1 >> 2) & 63) == lane) {
                        const int k = ((j1 >> 8) << 2) | (j1 & 3);
                        v_[k] -= (m2 - m1);
                    }

                    // steal j1
                    const int disp = row4col[j1];   // broadcast LDS read
                    if (lane == 0) {
                        row4col[j1]  = cur;
                        col4row[cur] = j1;
                        if (disp >= 0) col4row[disp] = -1;
                    }
                    if (disp < 0) { cur = -1; break; }
                    cur = disp;
                }
                // if chain guard exhausted, 'cur' stays unmatched -> Dijkstra
            }
        }
    }

    // unmatched-row bitmasks for Dijkstra (ascending order)
    unsigned long long um0 = ~__ballot(col4row[lane] >= 0);
    unsigned long long um1 = ~__ballot(col4row[lane + 64] >= 0);

    for (int half = 0; half < 2; ++half) {
        unsigned long long mask = half ? um1 : um0;
        while (mask) {
            const int curRow = __ffsll(mask) - 1 + 64 * half;
            mask &= mask - 1;

            #pragma unroll
            for (int k = 0; k < 16; ++k) dist_[k] = FINF;
            unsigned used  = 0;          // SC bitmask, bit k
            float    minVal = 0.0f;
            int      i_s  = curRow;
            int      sink = -1;
            int      cnt  = 0;

            for (int guard = 0; guard <= M; ++guard) {
                const float ui = u_sh[i_s];
                const float s  = minVal - ui;

                float4 c4[4];
                if (USET) {
                    const float4* row = (const float4*)(CbTB + (size_t)i_s * Q);
                    #pragma unroll
                    for (int g = 0; g < 4; ++g) c4[g] = row[lane + 64 * g];
                } else {
                    const float* col = CbB + i_s;
                    #pragma unroll
                    for (int g = 0; g < 4; ++g) {
                        float* cf = (float*)&c4[g];
                        #pragma unroll
                        for (int e = 0; e < 4; ++e)
                            cf[e] = col[(size_t)(256 * g + 4 * lane + e) * T];
                    }
                }

                // relax free columns + per-lane argmin
                float lmin = FINF; int lidx = 0;
                #pragma unroll
                for (int g = 0; g < 4; ++g) {
                    const float* cf = (const float*)&c4[g];
                    #pragma unroll
                    for (int e = 0; e < 4; ++e) {
                        const int k = 4 * g + e;
                        const int j = 256 * g + 4 * lane + e;
                        const bool fr = ((used >> k) & 1u) == 0u;
                        float r = s + cf[e] - v_[k];
                        if (fr && r < dist_[k]) {
                            dist_[k] = r;
                            path_lds[256 * g + 64 * e + lane] = i_s;  // swizzled
                        }
                        float a = fr ? dist_[k] : FINF;
                        if (a < lmin) { lmin = a; lidx = j; }
                    }
                }

                // speculative owner lookup (hides row4col LDS latency)
                const int cand = row4col[lidx];

                unsigned lmono = mono_enc(lmin);
                unsigned rmin = lmono;
                DPP_UMIN_REDUCE(rmin);
                const unsigned gmin =
                    (unsigned)__builtin_amdgcn_readlane((int)rmin, 63);

                const unsigned long long bmask = __ballot(lmono == gmin);
                const int winner = __ffsll(bmask) - 1;

                minVal = __uint_as_float(
                    (unsigned)__builtin_amdgcn_readlane(
                        (int)__float_as_uint(lmin), winner));
                const int jstar = __builtin_amdgcn_readlane(lidx, winner);

                if (((jstar >> 2) & 63) == lane)
                    used |= (1u << (((jstar >> 8) << 2) | (jstar & 3)));

                const int ra = __builtin_amdgcn_readlane(cand, winner);
                if (ra == -1) { sink = jstar; break; }
                if (lane == 0 && cnt < NR) { SRr[cnt] = ra; SRd[cnt] = minVal; }
                cnt++;
                i_s = ra;
            }

            // dual updates (scipy style, out of loop)
            #pragma unroll
            for (int k = 0; k < 16; ++k)
                if ((used >> k) & 1u) v_[k] += dist_[k] - minVal;

            if (lane == 0) u_sh[curRow] += minVal;
            for (int t = lane; t < cnt; t += 64)
                u_sh[SRr[t]] += minVal - SRd[t];

            // augment along path (serial, lane 0)
            if (lane == 0) {
                int j = sink;
                for (int g2 = 0; g2 < NR + 2; ++g2) {
                    int pi = path_lds[((j >> 8) << 8) | ((j & 3) << 6) |
                                      ((j >> 2) & 63)];
                    row4col[j] = pi;
                    int jn = col4row[pi];
                    col4row[pi] = j;
                    if (pi == curRow) break;
                    j = jn;
                }
            }
            __syncthreads();
        }
    }

    // output: rank(j) = #matched j' < j, via ballot prefix counts.
    int base = 0;
    #pragma unroll
    for (int g = 0; g < 4; ++g) {
        int tv[4], mt[4];
        #pragma unroll
        for (int e = 0; e < 4; ++e) {
            const int j = 256 * g + 4 * lane + e;
            tv[e] = row4col[j];
            mt[e] = (tv[e] >= 0);
        }
        unsigned long long B[4];
        #pragma unroll
        for (int e = 0; e < 4; ++e) B[e] = __ballot(mt[e] != 0);
        const unsigned long long low = (1ull << lane) - 1ull;
        int below = base;
        #pragma unroll
        for (int e = 0; e < 4; ++e) below += __popcll(B[e] & low);
        int local = 0;
        #pragma unroll
        for (int e = 0; e < 4; ++e) {
            if (mt[e]) {
                const int rank = below + local;
                const int j = 256 * g + 4 * lane + e;
                out_rows[b * NR + rank] = (float)j;
                out_cols[b * NR + rank] = (float)tv[e];
                ++local;
            }
        }
        #pragma unroll
        for (int e = 0; e < 4; ++e) base += __popcll(B[e]);
    }
}

// ---------------------------------------------------------------------------
extern "C" void kernel_launch(void* const* d_in, const int* in_sizes, int n_in,
                              void* d_out, int out_size, void* d_ws, size_t ws_size,
                              hipStream_t stream) {
    const float* logits = (const float*)d_in[0];
    const float* ppts   = (const float*)d_in[1];
    const int*   tlab   = (const int*)  d_in[2];
    const float* tpts   = (const float*)d_in[3];

    float* Cb   = (float*)d_out;                 // BS*Q*T floats
    float* rows = Cb + (size_t)BS * Q * T;       // BS*T floats
    float* cols = rows + (size_t)BS * T;         // BS*T floats

    float* CbT = (float*)d_ws;                               // 8 MiB
    unsigned long long* part =
        (unsigned long long*)((char*)d_ws + (size_t)BS * NR * Q * sizeof(float));

    const size_t need = (size_t)BS * NR * Q * sizeof(float)
                      + (size_t)BS * NQB * NR * sizeof(unsigned long long);

    if (ws_size >= need) {
        prep_kernel<<<BS * NQB, 256, 0, stream>>>(logits, ppts, tlab, tpts,
                                                  Cb, CbT, part);
        solve_kernel<1><<<BS, 64, 0, stream>>>(Cb, CbT, part, rows, cols);
    } else {
        cost_kernel<<<4096, 256, 0, stream>>>(logits, ppts, tlab, tpts, Cb);
        solve_kernel<0><<<BS, 64, 0, stream>>>(Cb, CbT, nullptr, rows, cols);
    }
}

// Round 10
// 124.668 us; speedup vs baseline: 1.3420x; 1.0244x over previous
//
#include <hip/hip_runtime.h>
#include <hip/hip_bf16.h>
#include <math.h>

#define BS 16
#define Q 1024
#define CC 92
#define T 128
#define M 1024   // columns in transposed problem (= Q)
#define NR 128   // rows in transposed problem (= T)
#define NQB 16   // q-blocks of 64 per batch

// ---------------------------------------------------------------------------
// Fused prep kernel: one block per (b, 64-q slab). Bit-identical Cb.
// (unchanged from R9)
// ---------------------------------------------------------------------------
__global__ __launch_bounds__(256) void prep_kernel(
    const float* __restrict__ logits,   // [BS][Q][CC]
    const float* __restrict__ ppts,     // [BS][Q][2]
    const int*   __restrict__ tlab,     // [BS][T]
    const float* __restrict__ tpts,     // [BS][T][2]
    float* __restrict__ Cb,             // [BS][Q][T]
    float* __restrict__ CbT,            // [BS][NR][Q]
    unsigned long long* __restrict__ part)  // [BS][NQB][NR]
{
    const int blk = blockIdx.x;         // 0..BS*NQB-1
    const int b   = blk & 15;           // XCD swizzle: blk%8 == b%8
    const int qb  = blk >> 4;
    const int q0  = qb * 64;
    const int tid = threadIdx.x;
    const int lane = tid & 63;

    __shared__ float lg[64 * CC];       // logits slab, [ql][c]
    __shared__ float tile[128][68];     // [t][ql], pitch 68 for b128 align
    __shared__ float tx_sh[T], ty_sh[T];
    __shared__ int   lab_sh[T];
    __shared__ float mx_sh[64], inv_sh[64], px_sh[64], py_sh[64];

    if (tid < T) {
        lab_sh[tid] = tlab[b * T + tid];
        tx_sh[tid]  = tpts[(b * T + tid) * 2 + 0];
        ty_sh[tid]  = tpts[(b * T + tid) * 2 + 1];
    }
    if (tid < 64) {
        px_sh[tid] = ppts[((size_t)b * Q + q0 + tid) * 2 + 0];
        py_sh[tid] = ppts[((size_t)b * Q + q0 + tid) * 2 + 1];
    }
    const float* lbase = logits + ((size_t)b * Q + q0) * CC;
    for (int idx = tid; idx < 64 * CC; idx += 256) lg[idx] = lbase[idx];
    __syncthreads();

    // softmax stats: EXACT same op sequence as original cost kernel.
    {
        const int w = tid >> 6;
        for (int s = 0; s < 16; ++s) {
            const int ql = w * 16 + s;
            const float* c = &lg[ql * CC];
            float l0 = c[lane];
            float l1 = (lane + 64 < CC) ? c[lane + 64] : -INFINITY;
            float mx = fmaxf(l0, l1);
            #pragma unroll
            for (int off = 32; off > 0; off >>= 1)
                mx = fmaxf(mx, __shfl_down(mx, off));
            mx = __shfl(mx, 0);
            float es = expf(l0 - mx) + ((lane + 64 < CC) ? expf(l1 - mx) : 0.0f);
            #pragma unroll
            for (int off = 32; off > 0; off >>= 1) es += __shfl_down(es, off);
            es = __shfl(es, 0);
            if (lane == 0) { mx_sh[ql] = mx; inv_sh[ql] = 1.0f / es; }
        }
    }
    __syncthreads();

    // tile compute + Cb write: thread = (ql = tid>>2, tc = tid&3)
    {
        const int ql = tid >> 2;
        const int tc = tid & 3;
        const float px = px_sh[ql], py = py_sh[ql];
        const float mx = mx_sh[ql], inv = inv_sh[ql];
        const float* lgq = &lg[ql * CC];
        float* cbrow = Cb + ((size_t)b * Q + q0 + ql) * T + tc * 32;
        #pragma unroll
        for (int k = 0; k < 8; ++k) {
            float4 o;
            #pragma unroll
            for (int e = 0; e < 4; ++e) {
                const int t = tc * 32 + 4 * k + e;
                const int labv = lab_sh[t];
                float prob = expf(lgq[labv] - mx) * inv;
                float cp   = fabsf(px - tx_sh[t]) + fabsf(py - ty_sh[t]);
                float val  = cp - prob;
                (&o.x)[e] = val;
                tile[t][ql] = val;
            }
            ((float4*)cbrow)[k] = o;
        }
    }
    __syncthreads();

    // CbT write + rowmin partials: thread = (rg = tid>>4, c4 = tid&15)
    {
        const int rg = tid >> 4;
        const int c4 = tid & 15;
        #pragma unroll
        for (int it = 0; it < 8; ++it) {
            const int t = it * 16 + rg;
            float4 v = *(const float4*)&tile[t][4 * c4];
            *(float4*)(CbT + ((size_t)b * NR + t) * Q + q0 + 4 * c4) = v;

            unsigned long long bk = ~0ull;
            const float* vf = (const float*)&v;
            #pragma unroll
            for (int e = 0; e < 4; ++e) {
                unsigned bits = __float_as_uint(vf[e]);
                unsigned mono = (bits & 0x80000000u) ? ~bits
                                                     : (bits | 0x80000000u);
                const int j = q0 + 4 * c4 + e;
                unsigned long long key =
                    ((unsigned long long)mono << 10) | (unsigned)j;
                bk = (key < bk) ? key : bk;
            }
            #pragma unroll
            for (int off = 1; off < 16; off <<= 1) {
                unsigned long long ok = __shfl_xor(bk, off);
                bk = (ok < bk) ? ok : bk;
            }
            if (c4 == 0) part[((size_t)b * NQB + qb) * NR + t] = bk;
        }
    }
}

// ---------------------------------------------------------------------------
// Fallback cost kernel (only used if workspace is too small).
// ---------------------------------------------------------------------------
__global__ __launch_bounds__(256) void cost_kernel(
    const float* __restrict__ logits, const float* __restrict__ ppts,
    const int* __restrict__ tlab, const float* __restrict__ tpts,
    float* __restrict__ Cb)
{
    const int blk  = blockIdx.x;
    const int b    = blk >> 8;
    const int wave = threadIdx.x >> 6;
    const int lane = threadIdx.x & 63;
    const int q    = (blk & 255) * 4 + wave;

    __shared__ float tx_sh[T], ty_sh[T];
    __shared__ int   lab_sh[T];
    __shared__ float logit_sh[4][CC];

    if (threadIdx.x < T) {
        lab_sh[threadIdx.x] = tlab[b * T + threadIdx.x];
        tx_sh[threadIdx.x]  = tpts[(b * T + threadIdx.x) * 2 + 0];
        ty_sh[threadIdx.x]  = tpts[(b * T + threadIdx.x) * 2 + 1];
    }
    const float* lrow = logits + ((size_t)b * Q + q) * CC;
    float l0 = lrow[lane];
    float l1 = (lane + 64 < CC) ? lrow[lane + 64] : -INFINITY;
    logit_sh[wave][lane] = l0;
    if (lane + 64 < CC) logit_sh[wave][lane + 64] = l1;

    float mx = fmaxf(l0, l1);
    #pragma unroll
    for (int off = 32; off > 0; off >>= 1) mx = fmaxf(mx, __shfl_down(mx, off));
    mx = __shfl(mx, 0);
    float es = expf(l0 - mx) + ((lane + 64 < CC) ? expf(l1 - mx) : 0.0f);
    #pragma unroll
    for (int off = 32; off > 0; off >>= 1) es += __shfl_down(es, off);
    es = __shfl(es, 0);
    const float inv = 1.0f / es;
    const float px = ppts[((size_t)b * Q + q) * 2 + 0];
    const float py = ppts[((size_t)b * Q + q) * 2 + 1];
    __syncthreads();
    float* outrow = Cb + ((size_t)b * Q + q) * T;
    #pragma unroll
    for (int t = lane; t < T; t += 64) {
        int   labv = lab_sh[t];
        float prob = expf(logit_sh[wave][labv] - mx) * inv;
        float cp   = fabsf(px - tx_sh[t]) + fabsf(py - ty_sh[t]);
        outrow[t]  = cp - prob;
    }
}

// DPP wave64 umin reduce step: dest = min(x, x shifted by ctrl); OOB lanes
// keep old (= x), so they're no-ops. ctrl is a compile-time constant.
#define DPP_UMIN_STEP(x, ctrl)                                              \
    {                                                                       \
        unsigned _t = (unsigned)__builtin_amdgcn_update_dpp(                \
            (int)(x), (int)(x), (ctrl), 0xF, 0xF, false);                   \
        (x) = ((x) < _t) ? (x) : _t;                                        \
    }

#define DPP_UMIN_REDUCE(x)                                                  \
    DPP_UMIN_STEP(x, 0x111); DPP_UMIN_STEP(x, 0x112);                       \
    DPP_UMIN_STEP(x, 0x114); DPP_UMIN_STEP(x, 0x118);                       \
    DPP_UMIN_STEP(x, 0x142); DPP_UMIN_STEP(x, 0x143);

// Joint 2-min DPP step on sorted pairs (x1<=x2): merge with shifted pair.
// m1' = min(a1,b1); m2' = min(max(a1,b1), min(a2,b2)) — exact 2nd smallest
// of the combined multiset (identical values to two serialized reduces).
#define DPP_UMIN2_STEP(x1, x2, ctrl)                                        \
    {                                                                       \
        unsigned _t1 = (unsigned)__builtin_amdgcn_update_dpp(               \
            (int)(x1), (int)(x1), (ctrl), 0xF, 0xF, false);                 \
        unsigned _t2 = (unsigned)__builtin_amdgcn_update_dpp(               \
            (int)(x2), (int)(x2), (ctrl), 0xF, 0xF, false);                 \
        unsigned _hi = ((x1) > _t1) ? (x1) : _t1;                           \
        unsigned _lo2 = ((x2) < _t2) ? (x2) : _t2;                          \
        (x1) = ((x1) < _t1) ? (x1) : _t1;                                   \
        (x2) = (_hi < _lo2) ? _hi : _lo2;                                   \
    }

#define DPP_UMIN2_REDUCE(x1, x2)                                            \
    DPP_UMIN2_STEP(x1, x2, 0x111); DPP_UMIN2_STEP(x1, x2, 0x112);           \
    DPP_UMIN2_STEP(x1, x2, 0x114); DPP_UMIN2_STEP(x1, x2, 0x118);           \
    DPP_UMIN2_STEP(x1, x2, 0x142); DPP_UMIN2_STEP(x1, x2, 0x143);

__device__ __forceinline__ unsigned mono_enc(float f) {
    unsigned b = __float_as_uint(f);
    return (b & 0x80000000u) ? ~b : (b | 0x80000000u);
}
__device__ __forceinline__ float mono_dec(unsigned m) {
    unsigned b = (m & 0x80000000u) ? (m ^ 0x80000000u) : ~m;
    return __uint_as_float(b);
}

// ---------------------------------------------------------------------------
// Kernel 2: JV solver. ONE WAVE per batch.
// Phase A: rowmin-greedy init. Phase B: ART with shortened chain
// (speculative owner lookup + joint 2-min DPP reduce — identical values).
// Phase C: fp32 Dijkstra, byte-identical to R8/R9.
// ---------------------------------------------------------------------------
template<int USET>
__global__ __launch_bounds__(64) void solve_kernel(
    const float* __restrict__ Cb,    // [BS][Q][T] fallback (strided)
    const float* __restrict__ CbT,   // [BS][NR][Q] row-major solver cost
    const unsigned long long* __restrict__ part,  // [BS][NQB][NR] or nullptr
    float* __restrict__ out_rows,    // [BS][T]
    float* __restrict__ out_cols)    // [BS][T]
{
    const int b    = blockIdx.x;
    const int lane = threadIdx.x;    // 0..63

    __shared__ int    row4col[M];    // col j -> row (-1 free)
    __shared__ int    col4row[NR];   // row i -> col (-1 free)
    __shared__ float  u_sh[NR];
    __shared__ int    path_lds[M];   // swizzled: A(j) = 256g + 64e + L
    __shared__ int    SRr[NR];       // rows that joined SR (excl. curRow)
    __shared__ float  SRd[NR];       // dist at which they joined
    __shared__ int    minj_sh[NR];   // per-row argmin column
    __shared__ int    claim[M];      // col j -> lowest row claiming it

    const float* CbB  = Cb  + (size_t)b * Q * T;
    const float* CbTB = CbT + (size_t)b * NR * Q;

    for (int j = lane; j < M;  j += 64) { row4col[j] = -1; claim[j] = 0x7fffffff; }
    for (int i = lane; i < NR; i += 64) col4row[i] = -1;

    // decode rowmin partials (coalesced: lane-consecutive in r)
    if (part) {
        #pragma unroll
        for (int r2 = 0; r2 < 2; ++r2) {
            const int r = lane + 64 * r2;
            const unsigned long long* pr = part + (size_t)b * NQB * NR + r;
            unsigned long long k = pr[0];
            #pragma unroll
            for (int i = 1; i < NQB; ++i) {
                unsigned long long o = pr[(size_t)i * NR];
                k = (o < k) ? o : k;
            }
            minj_sh[r] = (int)(k & 1023u);
            u_sh[r] = mono_dec((unsigned)(k >> 10));
        }
    } else {
        for (int i = lane; i < NR; i += 64) { minj_sh[i] = -1; u_sh[i] = 0.0f; }
    }
    __syncthreads();

    // greedy: lowest row index wins its argmin column
    if (part) {
        #pragma unroll
        for (int r2 = 0; r2 < 2; ++r2) {
            const int r = lane + 64 * r2;
            atomicMin(&claim[minj_sh[r]], r);
        }
        __syncthreads();
        #pragma unroll
        for (int r2 = 0; r2 < 2; ++r2) {
            const int r = lane + 64 * r2;
            const int mj = minj_sh[r];
            if (claim[mj] == r) { col4row[r] = mj; row4col[mj] = r; }
        }
        __syncthreads();
    }

    const float FINF = INFINITY;
    float v_[16], dist_[16];
    #pragma unroll
    for (int k = 0; k < 16; ++k) v_[k] = 0.0f;

    // ---------------- Phase B: augmenting row reduction ------------------
    {
        unsigned long long am0 = ~__ballot(col4row[lane] >= 0);
        unsigned long long am1 = ~__ballot(col4row[lane + 64] >= 0);
        for (int half = 0; half < 2; ++half) {
            unsigned long long mask = half ? am1 : am0;
            while (mask) {
                int cur = __ffsll(mask) - 1 + 64 * half;
                mask &= mask - 1;

                for (int step = 0; step < 48; ++step) {
                    const float ucur = u_sh[cur];

                    float4 c4[4];
                    if (USET) {
                        const float4* row =
                            (const float4*)(CbTB + (size_t)cur * Q);
                        #pragma unroll
                        for (int g = 0; g < 4; ++g) c4[g] = row[lane + 64 * g];
                    } else {
                        const float* col = CbB + cur;
                        #pragma unroll
                        for (int g = 0; g < 4; ++g) {
                            float* cf = (float*)&c4[g];
                            #pragma unroll
                            for (int e = 0; e < 4; ++e)
                                cf[e] = col[(size_t)(256*g + 4*lane + e) * T];
                        }
                    }

                    // per-lane (m1, j1) and m2 of reduced costs
                    float m1l = FINF, m2l = FINF; int j1l = 0;
                    #pragma unroll
                    for (int g = 0; g < 4; ++g) {
                        const float* cf = (const float*)&c4[g];
                        #pragma unroll
                        for (int e = 0; e < 4; ++e) {
                            const int k = 4 * g + e;
                            const int j = 256 * g + 4 * lane + e;
                            float r = cf[e] - ucur - v_[k];
                            if (r < m1l) { m2l = m1l; m1l = r; j1l = j; }
                            else if (r < m2l) { m2l = r; }
                        }
                    }

                    // speculative owner lookup for this lane's candidate
                    // (hides the post-winner row4col read behind the reduce;
                    // wave-coherent with lane-0 steal writes: same wave,
                    // ordered DS ops)
                    const int cand = row4col[j1l];

                    // joint (m1, m2) 2-min DPP reduce — identical values to
                    // the two serialized reduces of R9
                    const unsigned lm1 = mono_enc(m1l);
                    unsigned e1 = lm1;
                    unsigned e2 = mono_enc(m2l);
                    DPP_UMIN2_REDUCE(e1, e2);
                    const unsigned g1 =
                        (unsigned)__builtin_amdgcn_readlane((int)e1, 63);
                    const unsigned g2 =
                        (unsigned)__builtin_amdgcn_readlane((int)e2, 63);
                    const float m1 = mono_dec(g1);
                    const float m2 = mono_dec(g2);

                    // winner lane (lowest lane on exact ties; ties measure-0)
                    const unsigned long long bm = __ballot(lm1 == g1);
                    const int winner = __ffsll(bm) - 1;
                    const int j1   = __builtin_amdgcn_readlane(j1l, winner);
                    const int disp = __builtin_amdgcn_readlane(cand, winner);

                    // dual update: u[cur] += m2 ; v[j1] -= (m2 - m1)
                    if (lane == 0) u_sh[cur] = ucur + m2;
                    if (((j1 >> 2) & 63) == lane) {
                        const int k = ((j1 >> 8) << 2) | (j1 & 3);
                        v_[k] -= (m2 - m1);
                    }

                    // steal j1
                    if (lane == 0) {
                        row4col[j1]  = cur;
                        col4row[cur] = j1;
                        if (disp >= 0) col4row[disp] = -1;
                    }
                    if (disp < 0) { cur = -1; break; }
                    cur = disp;
                }
                // if chain guard exhausted, 'cur' stays unmatched -> Dijkstra
            }
        }
    }

    // unmatched-row bitmasks for Dijkstra (ascending order)
    unsigned long long um0 = ~__ballot(col4row[lane] >= 0);
    unsigned long long um1 = ~__ballot(col4row[lane + 64] >= 0);

    for (int half = 0; half < 2; ++half) {
        unsigned long long mask = half ? um1 : um0;
        while (mask) {
            const int curRow = __ffsll(mask) - 1 + 64 * half;
            mask &= mask - 1;

            #pragma unroll
            for (int k = 0; k < 16; ++k) dist_[k] = FINF;
            unsigned used  = 0;          // SC bitmask, bit k
            float    minVal = 0.0f;
            int      i_s  = curRow;
            int      sink = -1;
            int      cnt  = 0;

            for (int guard = 0; guard <= M; ++guard) {
                const float ui = u_sh[i_s];
                const float s  = minVal - ui;

                float4 c4[4];
                if (USET) {
                    const float4* row = (const float4*)(CbTB + (size_t)i_s * Q);
                    #pragma unroll
                    for (int g = 0; g < 4; ++g) c4[g] = row[lane + 64 * g];
                } else {
                    const float* col = CbB + i_s;
                    #pragma unroll
                    for (int g = 0; g < 4; ++g) {
                        float* cf = (float*)&c4[g];
                        #pragma unroll
                        for (int e = 0; e < 4; ++e)
                            cf[e] = col[(size_t)(256 * g + 4 * lane + e) * T];
                    }
                }

                // relax free columns + per-lane argmin
                float lmin = FINF; int lidx = 0;
                #pragma unroll
                for (int g = 0; g < 4; ++g) {
                    const float* cf = (const float*)&c4[g];
                    #pragma unroll
                    for (int e = 0; e < 4; ++e) {
                        const int k = 4 * g + e;
                        const int j = 256 * g + 4 * lane + e;
                        const bool fr = ((used >> k) & 1u) == 0u;
                        float r = s + cf[e] - v_[k];
                        if (fr && r < dist_[k]) {
                            dist_[k] = r;
                            path_lds[256 * g + 64 * e + lane] = i_s;  // swizzled
                        }
                        float a = fr ? dist_[k] : FINF;
                        if (a < lmin) { lmin = a; lidx = j; }
                    }
                }

                // speculative owner lookup (hides row4col LDS latency)
                const int cand = row4col[lidx];

                unsigned lmono = mono_enc(lmin);
                unsigned rmin = lmono;
                DPP_UMIN_REDUCE(rmin);
                const unsigned gmin =
                    (unsigned)__builtin_amdgcn_readlane((int)rmin, 63);

                const unsigned long long bmask = __ballot(lmono == gmin);
                const int winner = __ffsll(bmask) - 1;

                minVal = __uint_as_float(
                    (unsigned)__builtin_amdgcn_readlane(
                        (int)__float_as_uint(lmin), winner));
                const int jstar = __builtin_amdgcn_readlane(lidx, winner);

                if (((jstar >> 2) & 63) == lane)
                    used |= (1u << (((jstar >> 8) << 2) | (jstar & 3)));

                const int ra = __builtin_amdgcn_readlane(cand, winner);
                if (ra == -1) { sink = jstar; break; }
                if (lane == 0 && cnt < NR) { SRr[cnt] = ra; SRd[cnt] = minVal; }
                cnt++;
                i_s = ra;
            }

            // dual updates (scipy style, out of loop)
            #pragma unroll
            for (int k = 0; k < 16; ++k)
                if ((used >> k) & 1u) v_[k] += dist_[k] - minVal;

            if (lane == 0) u_sh[curRow] += minVal;
            for (int t = lane; t < cnt; t += 64)
                u_sh[SRr[t]] += minVal - SRd[t];

            // augment along path (serial, lane 0)
            if (lane == 0) {
                int j = sink;
                for (int g2 = 0; g2 < NR + 2; ++g2) {
                    int pi = path_lds[((j >> 8) << 8) | ((j & 3) << 6) |
                                      ((j >> 2) & 63)];
                    row4col[j] = pi;
                    int jn = col4row[pi];
                    col4row[pi] = j;
                    if (pi == curRow) break;
                    j = jn;
                }
            }
            __syncthreads();
        }
    }

    // output: rank(j) = #matched j' < j, via ballot prefix counts.
    int base = 0;
    #pragma unroll
    for (int g = 0; g < 4; ++g) {
        int tv[4], mt[4];
        #pragma unroll
        for (int e = 0; e < 4; ++e) {
            const int j = 256 * g + 4 * lane + e;
            tv[e] = row4col[j];
            mt[e] = (tv[e] >= 0);
        }
        unsigned long long B[4];
        #pragma unroll
        for (int e = 0; e < 4; ++e) B[e] = __ballot(mt[e] != 0);
        const unsigned long long low = (1ull << lane) - 1ull;
        int below = base;
        #pragma unroll
        for (int e = 0; e < 4; ++e) below += __popcll(B[e] & low);
        int local = 0;
        #pragma unroll
        for (int e = 0; e < 4; ++e) {
            if (mt[e]) {
                const int rank = below + local;
                const int j = 256 * g + 4 * lane + e;
                out_rows[b * NR + rank] = (float)j;
                out_cols[b * NR + rank] = (float)tv[e];
                ++local;
            }
        }
        #pragma unroll
        for (int e = 0; e < 4; ++e) base += __popcll(B[e]);
    }
}

// ---------------------------------------------------------------------------
extern "C" void kernel_launch(void* const* d_in, const int* in_sizes, int n_in,
                              void* d_out, int out_size, void* d_ws, size_t ws_size,
                              hipStream_t stream) {
    const float* logits = (const float*)d_in[0];
    const float* ppts   = (const float*)d_in[1];
    const int*   tlab   = (const int*)  d_in[2];
    const float* tpts   = (const float*)d_in[3];

    float* Cb   = (float*)d_out;                 // BS*Q*T floats
    float* rows = Cb + (size_t)BS * Q * T;       // BS*T floats
    float* cols = rows + (size_t)BS * T;         // BS*T floats

    float* CbT = (float*)d_ws;                               // 8 MiB
    unsigned long long* part =
        (unsigned long long*)((char*)d_ws + (size_t)BS * NR * Q * sizeof(float));

    const size_t need = (size_t)BS * NR * Q * sizeof(float)
                      + (size_t)BS * NQB * NR * sizeof(unsigned long long);

    if (ws_size >= need) {
        prep_kernel<<<BS * NQB, 256, 0, stream>>>(logits, ppts, tlab, tpts,
                                                  Cb, CbT, part);
        solve_kernel<1><<<BS, 64, 0, stream>>>(Cb, CbT, part, rows, cols);
    } else {
        cost_kernel<<<4096, 256, 0, stream>>>(logits, ppts, tlab, tpts, Cb);
        solve_kernel<0><<<BS, 64, 0, stream>>>(Cb, CbT, nullptr, rows, cols);
    }
}